// Round 17
// baseline (1288.910 us; speedup 1.0000x reference)
//
#include <hip/hip_runtime.h>
#include <cstdint>
#include <cstddef>

#define DIM 512
#define NLAYERS 3
#define BM 128
#define BN 128
#define BK 32
#define BUF_E 12288   // elems per buffer: A 4096 + Bhi 4096 + Blo 4096 (24 KB)
#define BN_EPS 1e-5f

typedef float f32x4 __attribute__((ext_vector_type(4)));
typedef short bf16x8 __attribute__((ext_vector_type(8)));
typedef unsigned short u16x4 __attribute__((ext_vector_type(4)));
typedef unsigned short u16x8 __attribute__((ext_vector_type(8)));

__device__ __forceinline__ unsigned short f32_to_bf16(float f) {
    unsigned u = __float_as_uint(f);
    u += 0x7fffu + ((u >> 16) & 1u);
    return (unsigned short)(u >> 16);
}
__device__ __forceinline__ float bf16_to_f32(unsigned short h) {
    return __uint_as_float(((unsigned)h) << 16);
}

__device__ __forceinline__ void gl_lds16(const unsigned short* g, unsigned short* l) {
    __builtin_amdgcn_global_load_lds(
        (const __attribute__((address_space(1))) void*)g,
        (__attribute__((address_space(3))) void*)l,
        16, 0, 0);
}

__device__ __forceinline__ void bn_params(float ssum, float ssq, float g, float b,
                                          float invN, float& a, float& c) {
    float m = ssum * invN;
    float var = fmaxf(ssq * invN - m * m, 0.f);
    a = g * rsqrtf(var + BN_EPS);
    c = b - m * a;
}

// ---------------- CSR build ----------------
__global__ void csr_count(const int* __restrict__ ei, int* __restrict__ counts, int E) {
    int e = blockIdx.x * 256 + threadIdx.x;
    if (e < E) atomicAdd(&counts[ei[E + e]], 1);
}

__global__ void scan1(const int* __restrict__ counts, int* __restrict__ rowptr,
                      int* __restrict__ bsum, int N) {
    __shared__ int sh[256];
    int t = threadIdx.x;
    int i = blockIdx.x * 256 + t;
    int v = (i < N) ? counts[i] : 0;
    sh[t] = v;
    __syncthreads();
    for (int d = 1; d < 256; d <<= 1) {
        int u = (t >= d) ? sh[t - d] : 0;
        __syncthreads();
        sh[t] += u;
        __syncthreads();
    }
    if (i < N) rowptr[i] = sh[t] - v;
    if (t == 255) bsum[blockIdx.x] = sh[255];
}

__global__ void scan2(int* __restrict__ bsum, int NB) {
    __shared__ int sh[256];
    int t = threadIdx.x;
    int v = (t < NB) ? bsum[t] : 0;
    sh[t] = v;
    __syncthreads();
    for (int d = 1; d < 256; d <<= 1) {
        int u = (t >= d) ? sh[t - d] : 0;
        __syncthreads();
        sh[t] += u;
        __syncthreads();
    }
    if (t < NB) bsum[t] = sh[t] - v;
}

__global__ void scan3(const int* __restrict__ bsum, int* __restrict__ rowptr,
                      int* __restrict__ cursor, int N, int E) {
    int i = blockIdx.x * 256 + threadIdx.x;
    if (i < N) {
        int v = rowptr[i] + bsum[blockIdx.x];
        rowptr[i] = v;
        cursor[i] = v;
    }
    if (blockIdx.x == 0 && threadIdx.x == 0) rowptr[N] = E;
}

__global__ void csr_fill(const int* __restrict__ ei, int* __restrict__ cursor,
                         int* __restrict__ colsrc, int E) {
    int e = blockIdx.x * 256 + threadIdx.x;
    if (e < E) {
        int s = ei[e], d = ei[E + e];
        int p = atomicAdd(&cursor[d], 1);
        colsrc[p] = s;
    }
}

// ---------------- weight prep ----------------
__global__ void wprep(const float* __restrict__ W1, const float* __restrict__ W2,
                      unsigned short* __restrict__ Whi, unsigned short* __restrict__ Wlo) {
    int id = blockIdx.x * 256 + threadIdx.x;
    int mat = id >> 16;
    int k4 = (id >> 9) & 127;
    int n = id & 511;
    const float* W = (mat & 1) ? W2 : W1;
    const float* base = W + (size_t)(mat >> 1) * DIM * DIM;
    u16x4 h, l;
#pragma unroll
    for (int j = 0; j < 4; j++) {
        float v = base[(size_t)(k4 * 4 + j) * DIM + n];
        unsigned short hh = f32_to_bf16(v);
        h[j] = hh;
        l[j] = f32_to_bf16(v - bf16_to_f32(hh));
    }
    size_t o = ((size_t)mat * DIM + n) * DIM + k4 * 4;
    *reinterpret_cast<u16x4*>(Whi + o) = h;
    *reinterpret_cast<u16x4*>(Wlo + o) = l;
}

// ---------------- xprep: Xbf = bf16(x) ----------------
__global__ void xprep(const float* __restrict__ X, unsigned short* __restrict__ Xbf,
                      int total8) {
    int i = blockIdx.x * blockDim.x + threadIdx.x;
    int stride = gridDim.x * blockDim.x;
    for (; i < total8; i += stride) {
        f32x4 v0 = *reinterpret_cast<const f32x4*>(X + (size_t)i * 8);
        f32x4 v1 = *reinterpret_cast<const f32x4*>(X + (size_t)i * 8 + 4);
        u16x8 h;
#pragma unroll
        for (int j = 0; j < 4; j++) h[j] = f32_to_bf16(v0[j]);
#pragma unroll
        for (int j = 0; j < 4; j++) h[4 + j] = f32_to_bf16(v1[j]);
        __builtin_nontemporal_store(h, reinterpret_cast<u16x8*>(Xbf + (size_t)i * 8));
    }
}

// ---------------- aggregation over bf16 rows -> A-hi plane ----------------
template<int MODE>
__global__ void agg_b(const unsigned short* __restrict__ U,
                      const int* __restrict__ rowptr, const int* __restrict__ colsrc,
                      const float* __restrict__ s3sum, const float* __restrict__ s3sq,
                      const float* __restrict__ ngl, const float* __restrict__ nbl,
                      float invN,
                      unsigned short* __restrict__ Phi, int N) {
    int n = blockIdx.x;
    int c = threadIdx.x * 4;
    f32x4 a3, c3;
    if (MODE) {
#pragma unroll
        for (int j = 0; j < 4; j++) {
            float a, cc;
            bn_params(s3sum[c + j], s3sq[c + j], ngl[c + j], nbl[c + j], invN, a, cc);
            a3[j] = a; c3[j] = cc;
        }
    }
    auto ldT = [&](int r) -> f32x4 {
        u16x4 u = *reinterpret_cast<const u16x4*>(U + (size_t)r * DIM + c);
        f32x4 v;
#pragma unroll
        for (int j = 0; j < 4; j++) {
            float f = bf16_to_f32(u[j]);
            v[j] = MODE ? fmaxf(f * a3[j] + c3[j], 0.f) : f;
        }
        return v;
    };
    f32x4 acc = ldT(n);
    int e0 = rowptr[n], e1 = rowptr[n + 1];
    int e = e0;
    for (; e + 8 <= e1; e += 8) {
        int s0 = colsrc[e],     s1 = colsrc[e + 1], s2 = colsrc[e + 2], s3 = colsrc[e + 3];
        int s4 = colsrc[e + 4], s5 = colsrc[e + 5], s6 = colsrc[e + 6], s7 = colsrc[e + 7];
        f32x4 v0 = ldT(s0);
        f32x4 v1 = ldT(s1);
        f32x4 v2 = ldT(s2);
        f32x4 v3 = ldT(s3);
        f32x4 v4 = ldT(s4);
        f32x4 v5 = ldT(s5);
        f32x4 v6 = ldT(s6);
        f32x4 v7 = ldT(s7);
        acc += v0; acc += v1; acc += v2; acc += v3;
        acc += v4; acc += v5; acc += v6; acc += v7;
    }
    for (; e < e1; e++) acc += ldT(colsrc[e]);
    u16x4 h;
#pragma unroll
    for (int j = 0; j < 4; j++) h[j] = f32_to_bf16(acc[j]);
    *reinterpret_cast<u16x4*>(Phi + (size_t)n * DIM + c) = h;
}

// ---------------- convert: Phi = bf16(relu(bf16Y*a1 + c1)), params inlined ----------------
__global__ void convert_kernel(const unsigned short* __restrict__ Yb,
                               const float* __restrict__ s1sum, const float* __restrict__ s1sq,
                               const float* __restrict__ g1l, const float* __restrict__ be1l,
                               float invN,
                               unsigned short* __restrict__ Phi, int total8) {
    __shared__ float spa[DIM], spc[DIM];
    for (int d = threadIdx.x; d < DIM; d += 256) {
        float a, c;
        bn_params(s1sum[d], s1sq[d], g1l[d], be1l[d], invN, a, c);
        spa[d] = a; spc[d] = c;
    }
    __syncthreads();
    int i = blockIdx.x * blockDim.x + threadIdx.x;
    int stride = gridDim.x * blockDim.x;
    for (; i < total8; i += stride) {
        int cb = (i & 63) * 8;
        u16x8 y = *reinterpret_cast<const u16x8*>(Yb + (size_t)i * 8);
        u16x8 h;
#pragma unroll
        for (int j = 0; j < 8; j++) {
            float f = fmaxf(bf16_to_f32(y[j]) * spa[cb + j] + spc[cb + j], 0.f);
            h[j] = f32_to_bf16(f);
        }
        *reinterpret_cast<u16x8*>(Phi + (size_t)i * 8) = h;
    }
}

// ---------------- GEMM: 128x128, BK=32, 3-deep counted-vmcnt pipeline ----------
// Raw s_barrier (no __syncthreads -> no compiler vmcnt(0) drain). Each STAGE = 6
// gl_lds16/wave; s_waitcnt vmcnt(6) at top of iter t guarantees tile t landed while
// tile t+1's loads stay in flight across the barrier (T4). Tail uses vmcnt(0).
__global__ __launch_bounds__(256, 2)
void gemm_kernel(const unsigned short* __restrict__ Ahi,
                 const unsigned short* __restrict__ Bhi,
                 const unsigned short* __restrict__ Blo,
                 const float* __restrict__ bias,
                 unsigned short* __restrict__ Yb,
                 float* __restrict__ ssum, float* __restrict__ ssq,
                 int M) {
    __shared__ unsigned short lds[3 * BUF_E];   // 72 KB -> 2 blocks/CU

    const int tid = threadIdx.x;
    const int lane = tid & 63;
    const int wave = tid >> 6;
    const int wm = wave >> 1, wn = wave & 1;

    // bijective XCD swizzle: all 4 n-blocks of an m-panel on the same XCD
    const int b = blockIdx.x;
    const int xcd = b & 7;
    const int slot_ = b >> 3;
    const int g = (slot_ >> 2) * 8 + xcd;
    const int j = slot_ & 3;
    const int m0 = g * BM;
    const int n0 = j * BN;

    const int r15 = lane & 15;
    const int rslot = ((lane >> 4) ^ ((r15 >> 1) & 3)) * 8;   // swizzled k-chunk read

    f32x4 acc[4][4];
#pragma unroll
    for (int i = 0; i < 4; i++)
#pragma unroll
        for (int jj = 0; jj < 4; jj++) acc[i][jj] = (f32x4){0.f, 0.f, 0.f, 0.f};

    // STAGE: 512 16B-slots per operand; slot = i*256 + wave*64 + lane.
    // LDS dest arg is wave-uniform (HW adds lane*16); global source is per-lane,
    // pre-swizzled: chunk cp holds global chunk cp ^ ((row>>1)&3).
    auto STAGE = [&](int bi, int kt) {
        unsigned short* L = lds + bi * BUF_E;
#pragma unroll
        for (int i = 0; i < 2; i++) {
            int slotbase = i * 256 + wave * 64;
            int slot = slotbase + lane;
            int row = slot >> 2;
            int gc = ((slot & 3) ^ ((row >> 1) & 3)) * 8;
            gl_lds16(Ahi + (size_t)(m0 + row) * DIM + kt + gc, L + slotbase * 8);
            gl_lds16(Bhi + (size_t)(n0 + row) * DIM + kt + gc, L + 4096 + slotbase * 8);
            gl_lds16(Blo + (size_t)(n0 + row) * DIM + kt + gc, L + 8192 + slotbase * 8);
        }
    };

    auto COMPUTE = [&](int bi) {
        unsigned short* L = lds + bi * BUF_E;
        bf16x8 bh[4], bl[4];
#pragma unroll
        for (int nf = 0; nf < 4; nf++) {
            int rb = wn * 64 + nf * 16 + r15;
            int off = rb * 32 + rslot;
            bh[nf] = *reinterpret_cast<const bf16x8*>(&L[4096 + off]);
            bl[nf] = *reinterpret_cast<const bf16x8*>(&L[8192 + off]);
        }
#pragma unroll
        for (int mf = 0; mf < 4; mf++) {
            int ra = wm * 64 + mf * 16 + r15;
            bf16x8 a = *reinterpret_cast<const bf16x8*>(&L[ra * 32 + rslot]);
#pragma unroll
            for (int nf = 0; nf < 4; nf++) {
                acc[mf][nf] = __builtin_amdgcn_mfma_f32_16x16x32_bf16(a, bl[nf], acc[mf][nf], 0, 0, 0);
                acc[mf][nf] = __builtin_amdgcn_mfma_f32_16x16x32_bf16(a, bh[nf], acc[mf][nf], 0, 0, 0);
            }
        }
    };

    STAGE(0, 0);
    STAGE(1, BK);
#pragma unroll
    for (int t = 0; t < 15; t++) {
        asm volatile("s_waitcnt vmcnt(6)" ::: "memory");
        __builtin_amdgcn_sched_barrier(0);
        __builtin_amdgcn_s_barrier();
        __builtin_amdgcn_sched_barrier(0);
        if (t < 14) STAGE((t + 2) % 3, (t + 2) * BK);
        COMPUTE(t % 3);
    }
    asm volatile("s_waitcnt vmcnt(0)" ::: "memory");
    __builtin_amdgcn_sched_barrier(0);
    __builtin_amdgcn_s_barrier();
    __builtin_amdgcn_sched_barrier(0);
    COMPUTE(0);   // t = 15, 15 % 3 == 0

    // epilogue: bias add, bf16 store, column stats from exact fp32 accs
    const int ln16 = lane & 15;
    const int lg = lane >> 4;
#pragma unroll
    for (int nf = 0; nf < 4; nf++) {
        int col = n0 + wn * 64 + nf * 16 + ln16;
        float bv = bias[col];
        float s = 0.f, qq = 0.f;
#pragma unroll
        for (int mf = 0; mf < 4; mf++) {
#pragma unroll
            for (int r = 0; r < 4; r++) {
                int row = m0 + wm * 64 + mf * 16 + lg * 4 + r;
                if (row < M) {
                    float v = acc[mf][nf][r] + bv;
                    Yb[(size_t)row * DIM + col] = f32_to_bf16(v);
                    s += v; qq += v * v;
                }
            }
        }
        s += __shfl_xor(s, 16);
        s += __shfl_xor(s, 32);
        qq += __shfl_xor(qq, 16);
        qq += __shfl_xor(qq, 32);
        if (lg == 0) {
            atomicAdd(&ssum[col], s);
            atomicAdd(&ssq[col], qq);
        }
    }
}

// ---------------- ustats (l<2): u = relu(bn2(y2)), in-place U store + st3 ----------
__global__ void ustats_kernel(const unsigned short* __restrict__ Yb,
                              const float* __restrict__ s2sum, const float* __restrict__ s2sq,
                              const float* __restrict__ g2l, const float* __restrict__ be2l,
                              float invN,
                              float* __restrict__ s3sum, float* __restrict__ s3sq,
                              unsigned short* __restrict__ U,
                              int M, int chunk) {
    int d = blockIdx.x * blockDim.x + threadIdx.x;
    float a, c;
    bn_params(s2sum[d], s2sq[d], g2l[d], be2l[d], invN, a, c);
    int r0 = blockIdx.y * chunk;
    int r1 = r0 + chunk; if (r1 > M) r1 = M;
    float s = 0.f, q = 0.f;
    for (int r = r0; r < r1; r++) {
        size_t idx = (size_t)r * DIM + d;
        float v = fmaxf(bf16_to_f32(Yb[idx]) * a + c, 0.f);
        s += v; q += v * v;
        U[idx] = f32_to_bf16(v);
    }
    atomicAdd(&s3sum[d], s);
    atomicAdd(&s3sq[d], q);
}

// ---------------- params_final: analytic BN3 stats for the affine last layer ----------
__global__ void params_final(const float* __restrict__ s2sum, const float* __restrict__ s2sq,
                             const float* __restrict__ g2l, const float* __restrict__ be2l,
                             const float* __restrict__ ngl, const float* __restrict__ nbl,
                             float invN,
                             float* __restrict__ pa2, float* __restrict__ pc2,
                             float* __restrict__ pa3, float* __restrict__ pc3) {
    int d = threadIdx.x;
    float a2, c2;
    bn_params(s2sum[d], s2sq[d], g2l[d], be2l[d], invN, a2, c2);
    float m_y = s2sum[d] * invN;
    float var_y = fmaxf(s2sq[d] * invN - m_y * m_y, 0.f);
    float m_u = a2 * m_y + c2;
    float var_u = a2 * a2 * var_y;
    float a3 = ngl[d] * rsqrtf(var_u + BN_EPS);
    float c3 = nbl[d] - m_u * a3;
    pa2[d] = a2; pc2[d] = c2;
    pa3[d] = a3; pc3[d] = c3;
}

// ---------------- finalize: out_f32 = (bf16y*a2+c2)*a3+c3 ----------------
__global__ void finalize_kernel(const unsigned short* __restrict__ Yb,
                                const float* __restrict__ pa2, const float* __restrict__ pc2,
                                const float* __restrict__ pa3, const float* __restrict__ pc3,
                                float* __restrict__ out, int total4) {
    int i = blockIdx.x * blockDim.x + threadIdx.x;
    int stride = gridDim.x * blockDim.x;
    for (; i < total4; i += stride) {
        int c = (i & 127) * 4;
        u16x4 y = *reinterpret_cast<const u16x4*>(Yb + (size_t)i * 4);
        f32x4 v;
#pragma unroll
        for (int j = 0; j < 4; j++) {
            float f = bf16_to_f32(y[j]) * pa2[c + j] + pc2[c + j];
            v[j] = f * pa3[c + j] + pc3[c + j];
        }
        *reinterpret_cast<f32x4*>(out + (size_t)i * 4) = v;
    }
}

extern "C" void kernel_launch(void* const* d_in, const int* in_sizes, int n_in,
                              void* d_out, int out_size, void* d_ws, size_t ws_size,
                              hipStream_t stream) {
    const float* x   = (const float*)d_in[0];
    const int*   ei  = (const int*)d_in[1];
    const float* W1  = (const float*)d_in[2];
    const float* b1  = (const float*)d_in[3];
    const float* g1  = (const float*)d_in[4];
    const float* be1 = (const float*)d_in[5];
    const float* W2  = (const float*)d_in[6];
    const float* b2  = (const float*)d_in[7];
    const float* g2  = (const float*)d_in[8];
    const float* be2 = (const float*)d_in[9];
    const float* ng  = (const float*)d_in[10];
    const float* nb  = (const float*)d_in[11];

    const int N = in_sizes[0] / DIM;
    const int E = in_sizes[1] / 2;

    char* ws = (char*)d_ws;
    size_t off = 0;
    auto alloc = [&](size_t bytes) -> void* {
        void* p = ws + off;
        off += (bytes + 255) & ~(size_t)255;
        return p;
    };
    unsigned short* Phi = (unsigned short*)alloc((size_t)N * DIM * 2);
    unsigned short* Xbf = (unsigned short*)alloc((size_t)N * DIM * 2);   // absorbs pad-panel OOB reads
    unsigned short* Ybf = (unsigned short*)alloc((size_t)N * DIM * 2);   // y1 -> y2 -> U (in-place)
    unsigned short* Whi = (unsigned short*)alloc(6ull * DIM * DIM * 2);
    unsigned short* Wlo = (unsigned short*)alloc(6ull * DIM * DIM * 2);
    int* rowptr = (int*)alloc((size_t)(N + 1) * 4);
    int* counts = (int*)alloc((size_t)N * 4);
    int* cursor = (int*)alloc((size_t)N * 4);
    int* colsrc = (int*)alloc((size_t)E * 4);
    int* bsum   = (int*)alloc(1024 * 4);
    float* stats = (float*)alloc(9ull * 1024 * 4);
    float* prm = (float*)alloc(4ull * DIM * 4);

    float* Yout = (float*)d_out;
    float* pa2 = prm,          *pc2 = prm + DIM;
    float* pa3 = prm + 2*DIM,  *pc3 = prm + 3*DIM;

    hipMemsetAsync(counts, 0, (size_t)N * 4, stream);
    hipMemsetAsync(stats, 0, 9ull * 1024 * 4, stream);

    const int NBs = (N + 255) / 256;

    wprep<<<1536, 256, 0, stream>>>(W1, W2, Whi, Wlo);
    xprep<<<2048, 256, 0, stream>>>(x, Xbf, N * DIM / 8);
    csr_count<<<(E + 255) / 256, 256, 0, stream>>>(ei, counts, E);
    scan1<<<NBs, 256, 0, stream>>>(counts, rowptr, bsum, N);
    scan2<<<1, 256, 0, stream>>>(bsum, NBs);
    scan3<<<NBs, 256, 0, stream>>>(bsum, rowptr, cursor, N, E);
    csr_fill<<<(E + 255) / 256, 256, 0, stream>>>(ei, cursor, colsrc, E);

    const float invN = 1.0f / (float)N;
    const int Gm = (((N + BM - 1) / BM) + 7) & ~7;   // 391 -> 392 m-panels (mult of 8)
    const int gemm_blocks = Gm * 4;
    const int uchunk = (N + 199) / 200;
    const int total8 = N * DIM / 8;

    for (int l = 0; l < NLAYERS; l++) {
        float* st1 = stats + (size_t)l * 3 * 1024;
        float* st2 = st1 + 1024;
        float* st3 = st2 + 1024;
        if (l == 0)
            agg_b<0><<<N, 128, 0, stream>>>(Xbf, rowptr, colsrc,
                                            nullptr, nullptr, nullptr, nullptr, invN, Phi, N);
        else {
            float* p3 = stats + (size_t)(l - 1) * 3 * 1024 + 2048;   // prev layer st3
            agg_b<1><<<N, 128, 0, stream>>>(Ybf, rowptr, colsrc,
                                            p3, p3 + 512, ng + (l - 1) * DIM, nb + (l - 1) * DIM,
                                            invN, Phi, N);
        }
        gemm_kernel<<<gemm_blocks, 256, 0, stream>>>(Phi,
            Whi + (size_t)(l * 2) * DIM * DIM, Wlo + (size_t)(l * 2) * DIM * DIM,
            b1 + l * DIM, Ybf, st1, st1 + 512, N);
        convert_kernel<<<2048, 256, 0, stream>>>(Ybf, st1, st1 + 512,
                                                 g1 + l * DIM, be1 + l * DIM, invN,
                                                 Phi, total8);
        gemm_kernel<<<gemm_blocks, 256, 0, stream>>>(Phi,
            Whi + (size_t)(l * 2 + 1) * DIM * DIM, Wlo + (size_t)(l * 2 + 1) * DIM * DIM,
            b2 + l * DIM, Ybf, st2, st2 + 512, N);
        if (l < NLAYERS - 1)
            ustats_kernel<<<dim3(2, 200), 256, 0, stream>>>(Ybf, st2, st2 + 512,
                                                            g2 + l * DIM, be2 + l * DIM, invN,
                                                            st3, st3 + 512, Ybf, N, uchunk);
    }
    {
        int l = NLAYERS - 1;
        float* st2 = stats + (size_t)l * 3 * 1024 + 1024;
        params_final<<<1, 512, 0, stream>>>(st2, st2 + 512,
                                            g2 + l * DIM, be2 + l * DIM,
                                            ng + l * DIM, nb + l * DIM, invN,
                                            pa2, pc2, pa3, pc3);
    }
    finalize_kernel<<<2048, 256, 0, stream>>>(Ybf, pa2, pc2, pa3, pc3, Yout, N * DIM / 4);
}

// Round 18
// 1270.057 us; speedup vs baseline: 1.0148x; 1.0148x over previous
//
#include <hip/hip_runtime.h>
#include <cstdint>
#include <cstddef>

#define DIM 512
#define NLAYERS 3
#define BM 128
#define BN 128
#define BK 32
#define BUF_E 12288   // elems per buffer: A 4096 + Bhi 4096 + Blo 4096 (24 KB)
#define BN_EPS 1e-5f

typedef float f32x4 __attribute__((ext_vector_type(4)));
typedef short bf16x8 __attribute__((ext_vector_type(8)));
typedef unsigned short u16x4 __attribute__((ext_vector_type(4)));
typedef unsigned short u16x8 __attribute__((ext_vector_type(8)));

__device__ __forceinline__ unsigned short f32_to_bf16(float f) {
    unsigned u = __float_as_uint(f);
    u += 0x7fffu + ((u >> 16) & 1u);
    return (unsigned short)(u >> 16);
}
__device__ __forceinline__ float bf16_to_f32(unsigned short h) {
    return __uint_as_float(((unsigned)h) << 16);
}

__device__ __forceinline__ void gl_lds16(const unsigned short* g, unsigned short* l) {
    __builtin_amdgcn_global_load_lds(
        (const __attribute__((address_space(1))) void*)g,
        (__attribute__((address_space(3))) void*)l,
        16, 0, 0);
}

__device__ __forceinline__ void bn_params(float ssum, float ssq, float g, float b,
                                          float invN, float& a, float& c) {
    float m = ssum * invN;
    float var = fmaxf(ssq * invN - m * m, 0.f);
    a = g * rsqrtf(var + BN_EPS);
    c = b - m * a;
}

// ---------------- CSR build ----------------
__global__ void csr_count(const int* __restrict__ ei, int* __restrict__ counts, int E) {
    int e = blockIdx.x * 256 + threadIdx.x;
    if (e < E) atomicAdd(&counts[ei[E + e]], 1);
}

__global__ void scan1(const int* __restrict__ counts, int* __restrict__ rowptr,
                      int* __restrict__ bsum, int N) {
    __shared__ int sh[256];
    int t = threadIdx.x;
    int i = blockIdx.x * 256 + t;
    int v = (i < N) ? counts[i] : 0;
    sh[t] = v;
    __syncthreads();
    for (int d = 1; d < 256; d <<= 1) {
        int u = (t >= d) ? sh[t - d] : 0;
        __syncthreads();
        sh[t] += u;
        __syncthreads();
    }
    if (i < N) rowptr[i] = sh[t] - v;
    if (t == 255) bsum[blockIdx.x] = sh[255];
}

__global__ void scan2(int* __restrict__ bsum, int NB) {
    __shared__ int sh[256];
    int t = threadIdx.x;
    int v = (t < NB) ? bsum[t] : 0;
    sh[t] = v;
    __syncthreads();
    for (int d = 1; d < 256; d <<= 1) {
        int u = (t >= d) ? sh[t - d] : 0;
        __syncthreads();
        sh[t] += u;
        __syncthreads();
    }
    if (t < NB) bsum[t] = sh[t] - v;
}

__global__ void scan3(const int* __restrict__ bsum, int* __restrict__ rowptr,
                      int* __restrict__ cursor, int N, int E) {
    int i = blockIdx.x * 256 + threadIdx.x;
    if (i < N) {
        int v = rowptr[i] + bsum[blockIdx.x];
        rowptr[i] = v;
        cursor[i] = v;
    }
    if (blockIdx.x == 0 && threadIdx.x == 0) rowptr[N] = E;
}

__global__ void csr_fill(const int* __restrict__ ei, int* __restrict__ cursor,
                         int* __restrict__ colsrc, int E) {
    int e = blockIdx.x * 256 + threadIdx.x;
    if (e < E) {
        int s = ei[e], d = ei[E + e];
        int p = atomicAdd(&cursor[d], 1);
        colsrc[p] = s;
    }
}

// ---------------- fused prep: blocks <1536 split W; rest convert x -> bf16 ----------------
__global__ void prep_kernel(const float* __restrict__ W1, const float* __restrict__ W2,
                            const float* __restrict__ X,
                            unsigned short* __restrict__ Whi, unsigned short* __restrict__ Wlo,
                            unsigned short* __restrict__ Xbf, int total8) {
    if (blockIdx.x < 1536) {
        int id = blockIdx.x * 256 + threadIdx.x;
        int mat = id >> 16;
        int k4 = (id >> 9) & 127;
        int n = id & 511;
        const float* W = (mat & 1) ? W2 : W1;
        const float* base = W + (size_t)(mat >> 1) * DIM * DIM;
        u16x4 h, l;
#pragma unroll
        for (int j = 0; j < 4; j++) {
            float v = base[(size_t)(k4 * 4 + j) * DIM + n];
            unsigned short hh = f32_to_bf16(v);
            h[j] = hh;
            l[j] = f32_to_bf16(v - bf16_to_f32(hh));
        }
        size_t o = ((size_t)mat * DIM + n) * DIM + k4 * 4;
        *reinterpret_cast<u16x4*>(Whi + o) = h;
        *reinterpret_cast<u16x4*>(Wlo + o) = l;
    } else {
        int i = (blockIdx.x - 1536) * 256 + threadIdx.x;
        int stride = (gridDim.x - 1536) * 256;
        for (; i < total8; i += stride) {
            f32x4 v0 = *reinterpret_cast<const f32x4*>(X + (size_t)i * 8);
            f32x4 v1 = *reinterpret_cast<const f32x4*>(X + (size_t)i * 8 + 4);
            u16x8 h;
#pragma unroll
            for (int j = 0; j < 4; j++) h[j] = f32_to_bf16(v0[j]);
#pragma unroll
            for (int j = 0; j < 4; j++) h[4 + j] = f32_to_bf16(v1[j]);
            __builtin_nontemporal_store(h, reinterpret_cast<u16x8*>(Xbf + (size_t)i * 8));
        }
    }
}

// ---------------- aggregation over bf16 rows -> A-hi plane ----------------
template<int MODE>
__global__ void agg_b(const unsigned short* __restrict__ U,
                      const int* __restrict__ rowptr, const int* __restrict__ colsrc,
                      const float* __restrict__ s3sum, const float* __restrict__ s3sq,
                      const float* __restrict__ ngl, const float* __restrict__ nbl,
                      float invN,
                      unsigned short* __restrict__ Phi, int N) {
    int n = blockIdx.x;
    int c = threadIdx.x * 4;
    f32x4 a3, c3;
    if (MODE) {
#pragma unroll
        for (int j = 0; j < 4; j++) {
            float a, cc;
            bn_params(s3sum[c + j], s3sq[c + j], ngl[c + j], nbl[c + j], invN, a, cc);
            a3[j] = a; c3[j] = cc;
        }
    }
    auto ldT = [&](int r) -> f32x4 {
        u16x4 u = *reinterpret_cast<const u16x4*>(U + (size_t)r * DIM + c);
        f32x4 v;
#pragma unroll
        for (int j = 0; j < 4; j++) {
            float f = bf16_to_f32(u[j]);
            v[j] = MODE ? fmaxf(f * a3[j] + c3[j], 0.f) : f;
        }
        return v;
    };
    f32x4 acc = ldT(n);
    int e0 = rowptr[n], e1 = rowptr[n + 1];
    int e = e0;
    for (; e + 8 <= e1; e += 8) {
        int s0 = colsrc[e],     s1 = colsrc[e + 1], s2 = colsrc[e + 2], s3 = colsrc[e + 3];
        int s4 = colsrc[e + 4], s5 = colsrc[e + 5], s6 = colsrc[e + 6], s7 = colsrc[e + 7];
        f32x4 v0 = ldT(s0);
        f32x4 v1 = ldT(s1);
        f32x4 v2 = ldT(s2);
        f32x4 v3 = ldT(s3);
        f32x4 v4 = ldT(s4);
        f32x4 v5 = ldT(s5);
        f32x4 v6 = ldT(s6);
        f32x4 v7 = ldT(s7);
        acc += v0; acc += v1; acc += v2; acc += v3;
        acc += v4; acc += v5; acc += v6; acc += v7;
    }
    for (; e < e1; e++) acc += ldT(colsrc[e]);
    u16x4 h;
#pragma unroll
    for (int j = 0; j < 4; j++) h[j] = f32_to_bf16(acc[j]);
    *reinterpret_cast<u16x4*>(Phi + (size_t)n * DIM + c) = h;
}

// ---------------- GEMM1: 128x128, BK=32, 3-deep counted-vmcnt pipeline (R17, verified) ----
__global__ __launch_bounds__(256, 2)
void gemm_kernel(const unsigned short* __restrict__ Ahi,
                 const unsigned short* __restrict__ Bhi,
                 const unsigned short* __restrict__ Blo,
                 const float* __restrict__ bias,
                 unsigned short* __restrict__ Yb,
                 float* __restrict__ ssum, float* __restrict__ ssq,
                 int M) {
    __shared__ unsigned short lds[3 * BUF_E];   // 72 KB -> 2 blocks/CU

    const int tid = threadIdx.x;
    const int lane = tid & 63;
    const int wave = tid >> 6;
    const int wm = wave >> 1, wn = wave & 1;

    const int b = blockIdx.x;
    const int xcd = b & 7;
    const int slot_ = b >> 3;
    const int g = (slot_ >> 2) * 8 + xcd;
    const int j = slot_ & 3;
    const int m0 = g * BM;
    const int n0 = j * BN;

    const int r15 = lane & 15;
    const int rslot = ((lane >> 4) ^ ((r15 >> 1) & 3)) * 8;

    f32x4 acc[4][4];
#pragma unroll
    for (int i = 0; i < 4; i++)
#pragma unroll
        for (int jj = 0; jj < 4; jj++) acc[i][jj] = (f32x4){0.f, 0.f, 0.f, 0.f};

    auto STAGE = [&](int bi, int kt) {
        unsigned short* L = lds + bi * BUF_E;
#pragma unroll
        for (int i = 0; i < 2; i++) {
            int slotbase = i * 256 + wave * 64;
            int slot = slotbase + lane;
            int row = slot >> 2;
            int gc = ((slot & 3) ^ ((row >> 1) & 3)) * 8;
            gl_lds16(Ahi + (size_t)(m0 + row) * DIM + kt + gc, L + slotbase * 8);
            gl_lds16(Bhi + (size_t)(n0 + row) * DIM + kt + gc, L + 4096 + slotbase * 8);
            gl_lds16(Blo + (size_t)(n0 + row) * DIM + kt + gc, L + 8192 + slotbase * 8);
        }
    };

    auto COMPUTE = [&](int bi) {
        unsigned short* L = lds + bi * BUF_E;
        bf16x8 bh[4], bl[4];
#pragma unroll
        for (int nf = 0; nf < 4; nf++) {
            int rb = wn * 64 + nf * 16 + r15;
            int off = rb * 32 + rslot;
            bh[nf] = *reinterpret_cast<const bf16x8*>(&L[4096 + off]);
            bl[nf] = *reinterpret_cast<const bf16x8*>(&L[8192 + off]);
        }
#pragma unroll
        for (int mf = 0; mf < 4; mf++) {
            int ra = wm * 64 + mf * 16 + r15;
            bf16x8 a = *reinterpret_cast<const bf16x8*>(&L[ra * 32 + rslot]);
#pragma unroll
            for (int nf = 0; nf < 4; nf++) {
                acc[mf][nf] = __builtin_amdgcn_mfma_f32_16x16x32_bf16(a, bl[nf], acc[mf][nf], 0, 0, 0);
                acc[mf][nf] = __builtin_amdgcn_mfma_f32_16x16x32_bf16(a, bh[nf], acc[mf][nf], 0, 0, 0);
            }
        }
    };

    STAGE(0, 0);
    STAGE(1, BK);
#pragma unroll
    for (int t = 0; t < 15; t++) {
        asm volatile("s_waitcnt vmcnt(6)" ::: "memory");
        __builtin_amdgcn_sched_barrier(0);
        __builtin_amdgcn_s_barrier();
        __builtin_amdgcn_sched_barrier(0);
        if (t < 14) STAGE((t + 2) % 3, (t + 2) * BK);
        COMPUTE(t % 3);
    }
    asm volatile("s_waitcnt vmcnt(0)" ::: "memory");
    __builtin_amdgcn_sched_barrier(0);
    __builtin_amdgcn_s_barrier();
    __builtin_amdgcn_sched_barrier(0);
    COMPUTE(0);

    const int ln16 = lane & 15;
    const int lg = lane >> 4;
#pragma unroll
    for (int nf = 0; nf < 4; nf++) {
        int col = n0 + wn * 64 + nf * 16 + ln16;
        float bv = bias[col];
        float s = 0.f, qq = 0.f;
#pragma unroll
        for (int mf = 0; mf < 4; mf++) {
#pragma unroll
            for (int r = 0; r < 4; r++) {
                int row = m0 + wm * 64 + mf * 16 + lg * 4 + r;
                if (row < M) {
                    float v = acc[mf][nf][r] + bv;
                    Yb[(size_t)row * DIM + col] = f32_to_bf16(v);
                    s += v; qq += v * v;
                }
            }
        }
        s += __shfl_xor(s, 16);
        s += __shfl_xor(s, 32);
        qq += __shfl_xor(qq, 16);
        qq += __shfl_xor(qq, 32);
        if (lg == 0) {
            atomicAdd(&ssum[col], s);
            atomicAdd(&ssq[col], qq);
        }
    }
}

// ---------------- GEMM2: fused convert — A = bf16(relu(bn1(y1))) built in-staging ---------
// Reg-staged A (load y1, affine+relu from block-local BN1 params, ds_write to the same
// linear LDS slot gl_lds would fill); B via gl_lds16. Produces bit-identical A to the
// old convert pass. 52 KB LDS -> 3 blocks/CU. Plain dbuf + __syncthreads.
__global__ __launch_bounds__(256, 3)
void gemm2_kernel(const unsigned short* __restrict__ Yin,
                  const float* __restrict__ s1sum, const float* __restrict__ s1sq,
                  const float* __restrict__ g1l, const float* __restrict__ be1l,
                  float invN,
                  const unsigned short* __restrict__ Bhi,
                  const unsigned short* __restrict__ Blo,
                  const float* __restrict__ bias,
                  unsigned short* __restrict__ Yb,
                  float* __restrict__ ssum, float* __restrict__ ssq,
                  int M) {
    __shared__ unsigned short lds[2 * BUF_E];   // 48 KB
    __shared__ float spa[DIM], spc[DIM];        // +4 KB

    const int tid = threadIdx.x;
    const int lane = tid & 63;
    const int wave = tid >> 6;
    const int wm = wave >> 1, wn = wave & 1;

    for (int d = tid; d < DIM; d += 256) {
        float a, c;
        bn_params(s1sum[d], s1sq[d], g1l[d], be1l[d], invN, a, c);
        spa[d] = a; spc[d] = c;
    }
    __syncthreads();

    const int b = blockIdx.x;
    const int xcd = b & 7;
    const int slot_ = b >> 3;
    const int g = (slot_ >> 2) * 8 + xcd;
    const int j = slot_ & 3;
    const int m0 = g * BM;
    const int n0 = j * BN;

    const int r15 = lane & 15;
    const int rslot = ((lane >> 4) ^ ((r15 >> 1) & 3)) * 8;

    f32x4 acc[4][4];
#pragma unroll
    for (int i = 0; i < 4; i++)
#pragma unroll
        for (int jj = 0; jj < 4; jj++) acc[i][jj] = (f32x4){0.f, 0.f, 0.f, 0.f};

    auto STAGE = [&](int bi, int kt) {
        unsigned short* L = lds + bi * BUF_E;
#pragma unroll
        for (int i = 0; i < 2; i++) {
            int slotbase = i * 256 + wave * 64;
            int slot = slotbase + lane;
            int row = slot >> 2;
            int gc = ((slot & 3) ^ ((row >> 1) & 3));
            int colb = kt + gc * 8;
            // A: reg-stage + transform (== old convert, bit-identical)
            u16x8 y = *reinterpret_cast<const u16x8*>(Yin + (size_t)(m0 + row) * DIM + colb);
            f32x4 a0 = *reinterpret_cast<const f32x4*>(&spa[colb]);
            f32x4 a1 = *reinterpret_cast<const f32x4*>(&spa[colb + 4]);
            f32x4 c0 = *reinterpret_cast<const f32x4*>(&spc[colb]);
            f32x4 c1 = *reinterpret_cast<const f32x4*>(&spc[colb + 4]);
            u16x8 h;
#pragma unroll
            for (int jj = 0; jj < 4; jj++)
                h[jj] = f32_to_bf16(fmaxf(bf16_to_f32(y[jj]) * a0[jj] + c0[jj], 0.f));
#pragma unroll
            for (int jj = 0; jj < 4; jj++)
                h[4 + jj] = f32_to_bf16(fmaxf(bf16_to_f32(y[4 + jj]) * a1[jj] + c1[jj], 0.f));
            *reinterpret_cast<u16x8*>(&L[slot * 8]) = h;
            // B: async direct
            gl_lds16(Bhi + (size_t)(n0 + row) * DIM + colb, L + 4096 + slotbase * 8);
            gl_lds16(Blo + (size_t)(n0 + row) * DIM + colb, L + 8192 + slotbase * 8);
        }
    };

    auto COMPUTE = [&](int bi) {
        unsigned short* L = lds + bi * BUF_E;
        bf16x8 bh[4], bl[4];
#pragma unroll
        for (int nf = 0; nf < 4; nf++) {
            int rb = wn * 64 + nf * 16 + r15;
            int off = rb * 32 + rslot;
            bh[nf] = *reinterpret_cast<const bf16x8*>(&L[4096 + off]);
            bl[nf] = *reinterpret_cast<const bf16x8*>(&L[8192 + off]);
        }
#pragma unroll
        for (int mf = 0; mf < 4; mf++) {
            int ra = wm * 64 + mf * 16 + r15;
            bf16x8 a = *reinterpret_cast<const bf16x8*>(&L[ra * 32 + rslot]);
#pragma unroll
            for (int nf = 0; nf < 4; nf++) {
                acc[mf][nf] = __builtin_amdgcn_mfma_f32_16x16x32_bf16(a, bl[nf], acc[mf][nf], 0, 0, 0);
                acc[mf][nf] = __builtin_amdgcn_mfma_f32_16x16x32_bf16(a, bh[nf], acc[mf][nf], 0, 0, 0);
            }
        }
    };

    STAGE(0, 0);
    __syncthreads();
    int buf = 0;
#pragma unroll
    for (int t = 0; t < 16; t++) {
        if (t < 15) STAGE(buf ^ 1, (t + 1) * BK);
        COMPUTE(buf);
        __syncthreads();
        buf ^= 1;
    }

    const int ln16 = lane & 15;
    const int lg = lane >> 4;
#pragma unroll
    for (int nf = 0; nf < 4; nf++) {
        int col = n0 + wn * 64 + nf * 16 + ln16;
        float bv = bias[col];
        float s = 0.f, qq = 0.f;
#pragma unroll
        for (int mf = 0; mf < 4; mf++) {
#pragma unroll
            for (int r = 0; r < 4; r++) {
                int row = m0 + wm * 64 + mf * 16 + lg * 4 + r;
                if (row < M) {
                    float v = acc[mf][nf][r] + bv;
                    Yb[(size_t)row * DIM + col] = f32_to_bf16(v);
                    s += v; qq += v * v;
                }
            }
        }
        s += __shfl_xor(s, 16);
        s += __shfl_xor(s, 32);
        qq += __shfl_xor(qq, 16);
        qq += __shfl_xor(qq, 32);
        if (lg == 0) {
            atomicAdd(&ssum[col], s);
            atomicAdd(&ssq[col], qq);
        }
    }
}

// ---------------- ustats (l<2): u = relu(bn2(y2)), in-place U store + st3 ----------
__global__ void ustats_kernel(const unsigned short* __restrict__ Yb,
                              const float* __restrict__ s2sum, const float* __restrict__ s2sq,
                              const float* __restrict__ g2l, const float* __restrict__ be2l,
                              float invN,
                              float* __restrict__ s3sum, float* __restrict__ s3sq,
                              unsigned short* __restrict__ U,
                              int M, int chunk) {
    int d = blockIdx.x * blockDim.x + threadIdx.x;
    float a, c;
    bn_params(s2sum[d], s2sq[d], g2l[d], be2l[d], invN, a, c);
    int r0 = blockIdx.y * chunk;
    int r1 = r0 + chunk; if (r1 > M) r1 = M;
    float s = 0.f, q = 0.f;
    for (int r = r0; r < r1; r++) {
        size_t idx = (size_t)r * DIM + d;
        float v = fmaxf(bf16_to_f32(Yb[idx]) * a + c, 0.f);
        s += v; q += v * v;
        U[idx] = f32_to_bf16(v);
    }
    atomicAdd(&s3sum[d], s);
    atomicAdd(&s3sq[d], q);
}

// ---------------- finalize (+ inlined analytic last-layer BN params) ----------------
// u = a2*y + c2 (no relu) -> mean_u = a2*m_y + c2, var_u = a2^2*var_y (exact).
__global__ void finalize_kernel(const unsigned short* __restrict__ Yb,
                                const float* __restrict__ s2sum, const float* __restrict__ s2sq,
                                const float* __restrict__ g2l, const float* __restrict__ be2l,
                                const float* __restrict__ ngl, const float* __restrict__ nbl,
                                float invN,
                                float* __restrict__ out, int total4) {
    __shared__ float sa2[DIM], sc2[DIM], sa3[DIM], sc3[DIM];
    for (int d = threadIdx.x; d < DIM; d += 256) {
        float a2, c2;
        bn_params(s2sum[d], s2sq[d], g2l[d], be2l[d], invN, a2, c2);
        float m_y = s2sum[d] * invN;
        float var_y = fmaxf(s2sq[d] * invN - m_y * m_y, 0.f);
        float m_u = a2 * m_y + c2;
        float var_u = a2 * a2 * var_y;
        float a3 = ngl[d] * rsqrtf(var_u + BN_EPS);
        float c3 = nbl[d] - m_u * a3;
        sa2[d] = a2; sc2[d] = c2; sa3[d] = a3; sc3[d] = c3;
    }
    __syncthreads();
    int i = blockIdx.x * blockDim.x + threadIdx.x;
    int stride = gridDim.x * blockDim.x;
    for (; i < total4; i += stride) {
        int c = (i & 127) * 4;
        u16x4 y = *reinterpret_cast<const u16x4*>(Yb + (size_t)i * 4);
        f32x4 v;
#pragma unroll
        for (int j = 0; j < 4; j++) {
            float f = bf16_to_f32(y[j]) * sa2[c + j] + sc2[c + j];
            v[j] = f * sa3[c + j] + sc3[c + j];
        }
        *reinterpret_cast<f32x4*>(out + (size_t)i * 4) = v;
    }
}

extern "C" void kernel_launch(void* const* d_in, const int* in_sizes, int n_in,
                              void* d_out, int out_size, void* d_ws, size_t ws_size,
                              hipStream_t stream) {
    const float* x   = (const float*)d_in[0];
    const int*   ei  = (const int*)d_in[1];
    const float* W1  = (const float*)d_in[2];
    const float* b1  = (const float*)d_in[3];
    const float* g1  = (const float*)d_in[4];
    const float* be1 = (const float*)d_in[5];
    const float* W2  = (const float*)d_in[6];
    const float* b2  = (const float*)d_in[7];
    const float* g2  = (const float*)d_in[8];
    const float* be2 = (const float*)d_in[9];
    const float* ng  = (const float*)d_in[10];
    const float* nb  = (const float*)d_in[11];

    const int N = in_sizes[0] / DIM;
    const int E = in_sizes[1] / 2;

    char* ws = (char*)d_ws;
    size_t off = 0;
    auto alloc = [&](size_t bytes) -> void* {
        void* p = ws + off;
        off += (bytes + 255) & ~(size_t)255;
        return p;
    };
    // Buffer rotation: P0 (agg out / gemm1 A), P2=Xbf (x-bf16, then gemm2 out / U),
    // P1 (gemm1 out y1 = gemm2 A). Pad-panel OOB reads land in the next allocation.
    unsigned short* P0  = (unsigned short*)alloc((size_t)N * DIM * 2);
    unsigned short* P2  = (unsigned short*)alloc((size_t)N * DIM * 2);   // Xbf, then y2/U
    unsigned short* P1  = (unsigned short*)alloc((size_t)N * DIM * 2);
    unsigned short* Whi = (unsigned short*)alloc(6ull * DIM * DIM * 2);
    unsigned short* Wlo = (unsigned short*)alloc(6ull * DIM * DIM * 2);
    int* rowptr = (int*)alloc((size_t)(N + 1) * 4);
    int* counts = (int*)alloc((size_t)N * 4);
    int* cursor = (int*)alloc((size_t)N * 4);
    int* colsrc = (int*)alloc((size_t)E * 4);
    int* bsum   = (int*)alloc(1024 * 4);
    float* stats = (float*)alloc(9ull * 1024 * 4);

    float* Yout = (float*)d_out;

    hipMemsetAsync(counts, 0, (size_t)N * 4, stream);
    hipMemsetAsync(stats, 0, 9ull * 1024 * 4, stream);

    const int NBs = (N + 255) / 256;
    const int total8 = N * DIM / 8;

    prep_kernel<<<1536 + 1024, 256, 0, stream>>>(W1, W2, x, Whi, Wlo, P2, total8);
    csr_count<<<(E + 255) / 256, 256, 0, stream>>>(ei, counts, E);
    scan1<<<NBs, 256, 0, stream>>>(counts, rowptr, bsum, N);
    scan2<<<1, 256, 0, stream>>>(bsum, NBs);
    scan3<<<NBs, 256, 0, stream>>>(bsum, rowptr, cursor, N, E);
    csr_fill<<<(E + 255) / 256, 256, 0, stream>>>(ei, cursor, colsrc, E);

    const float invN = 1.0f / (float)N;
    const int Gm = (((N + BM - 1) / BM) + 7) & ~7;   // 392 m-panels
    const int gemm_blocks = Gm * 4;
    const int uchunk = (N + 199) / 200;

    for (int l = 0; l < NLAYERS; l++) {
        float* st1 = stats + (size_t)l * 3 * 1024;
        float* st2 = st1 + 1024;
        float* st3 = st2 + 1024;
        if (l == 0)
            agg_b<0><<<N, 128, 0, stream>>>(P2, rowptr, colsrc,
                                            nullptr, nullptr, nullptr, nullptr, invN, P0, N);
        else {
            float* p3 = stats + (size_t)(l - 1) * 3 * 1024 + 2048;   // prev layer st3
            agg_b<1><<<N, 128, 0, stream>>>(P2, rowptr, colsrc,
                                            p3, p3 + 512, ng + (l - 1) * DIM, nb + (l - 1) * DIM,
                                            invN, P0, N);
        }
        // gemm1: y1 = agg @ W1 + b1  (P0 -> P1)
        gemm_kernel<<<gemm_blocks, 256, 0, stream>>>(P0,
            Whi + (size_t)(l * 2) * DIM * DIM, Wlo + (size_t)(l * 2) * DIM * DIM,
            b1 + l * DIM, P1, st1, st1 + 512, N);
        // gemm2 (convert fused into A-staging): y2 = relu(bn1(y1)) @ W2 + b2  (P1 -> P2)
        gemm2_kernel<<<gemm_blocks, 256, 0, stream>>>(P1,
            st1, st1 + 512, g1 + l * DIM, be1 + l * DIM, invN,
            Whi + (size_t)(l * 2 + 1) * DIM * DIM, Wlo + (size_t)(l * 2 + 1) * DIM * DIM,
            b2 + l * DIM, P2, st2, st2 + 512, N);
        if (l < NLAYERS - 1)
            ustats_kernel<<<dim3(2, 200), 256, 0, stream>>>(P2, st2, st2 + 512,
                                                            g2 + l * DIM, be2 + l * DIM, invN,
                                                            st3, st3 + 512, P2, N, uchunk);
    }
    {
        int l = NLAYERS - 1;
        float* st2 = stats + (size_t)l * 3 * 1024 + 1024;
        finalize_kernel<<<2048, 256, 0, stream>>>(P2, st2, st2 + 512,
                                                  g2 + l * DIM, be2 + l * DIM,
                                                  ng + l * DIM, nb + l * DIM, invN,
                                                  Yout, N * DIM / 4);
    }
}

// Round 19
// 1131.302 us; speedup vs baseline: 1.1393x; 1.1227x over previous
//
#include <hip/hip_runtime.h>
#include <cstdint>
#include <cstddef>

#define DIM 512
#define NLAYERS 3
#define BM 128
#define BN 128
#define BK 32
#define BUF_E 8192    // elems per buffer: A 4096 + B 4096 (16 KB)
#define BN_EPS 1e-5f

typedef float f32x4 __attribute__((ext_vector_type(4)));
typedef _Float16 f16x8 __attribute__((ext_vector_type(8)));
typedef unsigned short u16x4 __attribute__((ext_vector_type(4)));
typedef unsigned short u16x8 __attribute__((ext_vector_type(8)));

__device__ __forceinline__ unsigned short f32_to_f16u(float f) {
    _Float16 h = (_Float16)f;
    return __builtin_bit_cast(unsigned short, h);
}
__device__ __forceinline__ float f16u_to_f32(unsigned short u) {
    return (float)__builtin_bit_cast(_Float16, u);
}

__device__ __forceinline__ void gl_lds16(const unsigned short* g, unsigned short* l) {
    __builtin_amdgcn_global_load_lds(
        (const __attribute__((address_space(1))) void*)g,
        (__attribute__((address_space(3))) void*)l,
        16, 0, 0);
}

__device__ __forceinline__ void bn_params(float ssum, float ssq, float g, float b,
                                          float invN, float& a, float& c) {
    float m = ssum * invN;
    float var = fmaxf(ssq * invN - m * m, 0.f);
    a = g * rsqrtf(var + BN_EPS);
    c = b - m * a;
}

// ---------------- CSR build ----------------
__global__ void csr_count(const int* __restrict__ ei, int* __restrict__ counts, int E) {
    int e = blockIdx.x * 256 + threadIdx.x;
    if (e < E) atomicAdd(&counts[ei[E + e]], 1);
}

__global__ void scan1(const int* __restrict__ counts, int* __restrict__ rowptr,
                      int* __restrict__ bsum, int N) {
    __shared__ int sh[256];
    int t = threadIdx.x;
    int i = blockIdx.x * 256 + t;
    int v = (i < N) ? counts[i] : 0;
    sh[t] = v;
    __syncthreads();
    for (int d = 1; d < 256; d <<= 1) {
        int u = (t >= d) ? sh[t - d] : 0;
        __syncthreads();
        sh[t] += u;
        __syncthreads();
    }
    if (i < N) rowptr[i] = sh[t] - v;
    if (t == 255) bsum[blockIdx.x] = sh[255];
}

__global__ void scan2(int* __restrict__ bsum, int NB) {
    __shared__ int sh[256];
    int t = threadIdx.x;
    int v = (t < NB) ? bsum[t] : 0;
    sh[t] = v;
    __syncthreads();
    for (int d = 1; d < 256; d <<= 1) {
        int u = (t >= d) ? sh[t - d] : 0;
        __syncthreads();
        sh[t] += u;
        __syncthreads();
    }
    if (t < NB) bsum[t] = sh[t] - v;
}

__global__ void scan3(const int* __restrict__ bsum, int* __restrict__ rowptr,
                      int* __restrict__ cursor, int N, int E) {
    int i = blockIdx.x * 256 + threadIdx.x;
    if (i < N) {
        int v = rowptr[i] + bsum[blockIdx.x];
        rowptr[i] = v;
        cursor[i] = v;
    }
    if (blockIdx.x == 0 && threadIdx.x == 0) rowptr[N] = E;
}

__global__ void csr_fill(const int* __restrict__ ei, int* __restrict__ cursor,
                         int* __restrict__ colsrc, int E) {
    int e = blockIdx.x * 256 + threadIdx.x;
    if (e < E) {
        int s = ei[e], d = ei[E + e];
        int p = atomicAdd(&cursor[d], 1);
        colsrc[p] = s;
    }
}

// ---------------- fused prep: blocks <1536 -> W fp16 transpose; rest -> x fp16 ----------
__global__ void prep_kernel(const float* __restrict__ W1, const float* __restrict__ W2,
                            const float* __restrict__ X,
                            unsigned short* __restrict__ Wf,
                            unsigned short* __restrict__ Xh, int total8) {
    if (blockIdx.x < 1536) {
        int id = blockIdx.x * 256 + threadIdx.x;
        int mat = id >> 16;
        int k4 = (id >> 9) & 127;
        int n = id & 511;
        const float* W = (mat & 1) ? W2 : W1;
        const float* base = W + (size_t)(mat >> 1) * DIM * DIM;
        u16x4 h;
#pragma unroll
        for (int j = 0; j < 4; j++)
            h[j] = f32_to_f16u(base[(size_t)(k4 * 4 + j) * DIM + n]);
        size_t o = ((size_t)mat * DIM + n) * DIM + k4 * 4;
        *reinterpret_cast<u16x4*>(Wf + o) = h;
    } else {
        int i = (blockIdx.x - 1536) * 256 + threadIdx.x;
        int stride = (gridDim.x - 1536) * 256;
        for (; i < total8; i += stride) {
            f32x4 v0 = *reinterpret_cast<const f32x4*>(X + (size_t)i * 8);
            f32x4 v1 = *reinterpret_cast<const f32x4*>(X + (size_t)i * 8 + 4);
            u16x8 h;
#pragma unroll
            for (int j = 0; j < 4; j++) h[j] = f32_to_f16u(v0[j]);
#pragma unroll
            for (int j = 0; j < 4; j++) h[4 + j] = f32_to_f16u(v1[j]);
            __builtin_nontemporal_store(h, reinterpret_cast<u16x8*>(Xh + (size_t)i * 8));
        }
    }
}

// ---------------- aggregation over fp16 rows -> fp16 A-plane ----------------
// MODE 0: T = identity.  MODE 1: T(v) = relu(v*a3+c3), params inlined from st3.
template<int MODE>
__global__ void agg_b(const unsigned short* __restrict__ U,
                      const int* __restrict__ rowptr, const int* __restrict__ colsrc,
                      const float* __restrict__ s3sum, const float* __restrict__ s3sq,
                      const float* __restrict__ ngl, const float* __restrict__ nbl,
                      float invN,
                      unsigned short* __restrict__ Phi, int N) {
    int n = blockIdx.x;
    int c = threadIdx.x * 4;
    f32x4 a3, c3;
    if (MODE) {
#pragma unroll
        for (int j = 0; j < 4; j++) {
            float a, cc;
            bn_params(s3sum[c + j], s3sq[c + j], ngl[c + j], nbl[c + j], invN, a, cc);
            a3[j] = a; c3[j] = cc;
        }
    }
    auto ldT = [&](int r) -> f32x4 {
        u16x4 u = *reinterpret_cast<const u16x4*>(U + (size_t)r * DIM + c);
        f32x4 v;
#pragma unroll
        for (int j = 0; j < 4; j++) {
            float f = f16u_to_f32(u[j]);
            v[j] = MODE ? fmaxf(f * a3[j] + c3[j], 0.f) : f;
        }
        return v;
    };
    f32x4 acc = ldT(n);
    int e0 = rowptr[n], e1 = rowptr[n + 1];
    int e = e0;
    for (; e + 8 <= e1; e += 8) {
        int s0 = colsrc[e],     s1 = colsrc[e + 1], s2 = colsrc[e + 2], s3 = colsrc[e + 3];
        int s4 = colsrc[e + 4], s5 = colsrc[e + 5], s6 = colsrc[e + 6], s7 = colsrc[e + 7];
        f32x4 v0 = ldT(s0);
        f32x4 v1 = ldT(s1);
        f32x4 v2 = ldT(s2);
        f32x4 v3 = ldT(s3);
        f32x4 v4 = ldT(s4);
        f32x4 v5 = ldT(s5);
        f32x4 v6 = ldT(s6);
        f32x4 v7 = ldT(s7);
        acc += v0; acc += v1; acc += v2; acc += v3;
        acc += v4; acc += v5; acc += v6; acc += v7;
    }
    for (; e < e1; e++) acc += ldT(colsrc[e]);
    u16x4 h;
#pragma unroll
    for (int j = 0; j < 4; j++) h[j] = f32_to_f16u(acc[j]);
    *reinterpret_cast<u16x4*>(Phi + (size_t)n * DIM + c) = h;
}

// ---------------- GEMM1: fp16 single-plane, 128x128, BK=32, dbuf ----------
__global__ __launch_bounds__(256, 4)
void gemm_kernel(const unsigned short* __restrict__ A,
                 const unsigned short* __restrict__ B,
                 const float* __restrict__ bias,
                 unsigned short* __restrict__ Yh,
                 float* __restrict__ ssum, float* __restrict__ ssq,
                 int M) {
    __shared__ unsigned short lds[2 * BUF_E];   // 32 KB

    const int tid = threadIdx.x;
    const int lane = tid & 63;
    const int wave = tid >> 6;
    const int wm = wave >> 1, wn = wave & 1;

    const int b = blockIdx.x;
    const int xcd = b & 7;
    const int slot_ = b >> 3;
    const int g = (slot_ >> 2) * 8 + xcd;
    const int j = slot_ & 3;
    const int m0 = g * BM;
    const int n0 = j * BN;

    const int r15 = lane & 15;
    const int rslot = ((lane >> 4) ^ ((r15 >> 1) & 3)) * 8;

    f32x4 acc[4][4];
#pragma unroll
    for (int i = 0; i < 4; i++)
#pragma unroll
        for (int jj = 0; jj < 4; jj++) acc[i][jj] = (f32x4){0.f, 0.f, 0.f, 0.f};

    auto STAGE = [&](int bi, int kt) {
        unsigned short* L = lds + bi * BUF_E;
#pragma unroll
        for (int i = 0; i < 2; i++) {
            int slotbase = i * 256 + wave * 64;
            int slot = slotbase + lane;
            int row = slot >> 2;
            int gc = ((slot & 3) ^ ((row >> 1) & 3)) * 8;
            gl_lds16(A + (size_t)(m0 + row) * DIM + kt + gc, L + slotbase * 8);
            gl_lds16(B + (size_t)(n0 + row) * DIM + kt + gc, L + 4096 + slotbase * 8);
        }
    };

    auto COMPUTE = [&](int bi) {
        unsigned short* L = lds + bi * BUF_E;
        f16x8 bf[4];
#pragma unroll
        for (int nf = 0; nf < 4; nf++) {
            int rb = wn * 64 + nf * 16 + r15;
            bf[nf] = *reinterpret_cast<const f16x8*>(&L[4096 + rb * 32 + rslot]);
        }
#pragma unroll
        for (int mf = 0; mf < 4; mf++) {
            int ra = wm * 64 + mf * 16 + r15;
            f16x8 a = *reinterpret_cast<const f16x8*>(&L[ra * 32 + rslot]);
#pragma unroll
            for (int nf = 0; nf < 4; nf++)
                acc[mf][nf] = __builtin_amdgcn_mfma_f32_16x16x32_f16(a, bf[nf], acc[mf][nf], 0, 0, 0);
        }
    };

    STAGE(0, 0);
    __syncthreads();
    int buf = 0;
#pragma unroll
    for (int t = 0; t < 16; t++) {
        if (t < 15) STAGE(buf ^ 1, (t + 1) * BK);
        COMPUTE(buf);
        __syncthreads();
        buf ^= 1;
    }

    const int ln16 = lane & 15;
    const int lg = lane >> 4;
#pragma unroll
    for (int nf = 0; nf < 4; nf++) {
        int col = n0 + wn * 64 + nf * 16 + ln16;
        float bv = bias[col];
        float s = 0.f, qq = 0.f;
#pragma unroll
        for (int mf = 0; mf < 4; mf++) {
#pragma unroll
            for (int r = 0; r < 4; r++) {
                int row = m0 + wm * 64 + mf * 16 + lg * 4 + r;
                if (row < M) {
                    float v = acc[mf][nf][r] + bv;
                    Yh[(size_t)row * DIM + col] = f32_to_f16u(v);
                    s += v; qq += v * v;
                }
            }
        }
        s += __shfl_xor(s, 16);
        s += __shfl_xor(s, 32);
        qq += __shfl_xor(qq, 16);
        qq += __shfl_xor(qq, 32);
        if (lg == 0) {
            atomicAdd(&ssum[col], s);
            atomicAdd(&ssq[col], qq);
        }
    }
}

// ---------------- GEMM2: A = f16(relu(bn1(y1))) fused in staging; B via gl_lds ----------
__global__ __launch_bounds__(256, 4)
void gemm2_kernel(const unsigned short* __restrict__ Yin,
                  const float* __restrict__ s1sum, const float* __restrict__ s1sq,
                  const float* __restrict__ g1l, const float* __restrict__ be1l,
                  float invN,
                  const unsigned short* __restrict__ B,
                  const float* __restrict__ bias,
                  unsigned short* __restrict__ Yh,
                  float* __restrict__ ssum, float* __restrict__ ssq,
                  int M) {
    __shared__ unsigned short lds[2 * BUF_E];   // 32 KB
    __shared__ float spa[DIM], spc[DIM];        // +4 KB

    const int tid = threadIdx.x;
    const int lane = tid & 63;
    const int wave = tid >> 6;
    const int wm = wave >> 1, wn = wave & 1;

    for (int d = tid; d < DIM; d += 256) {
        float a, c;
        bn_params(s1sum[d], s1sq[d], g1l[d], be1l[d], invN, a, c);
        spa[d] = a; spc[d] = c;
    }
    __syncthreads();

    const int b = blockIdx.x;
    const int xcd = b & 7;
    const int slot_ = b >> 3;
    const int g = (slot_ >> 2) * 8 + xcd;
    const int j = slot_ & 3;
    const int m0 = g * BM;
    const int n0 = j * BN;

    const int r15 = lane & 15;
    const int rslot = ((lane >> 4) ^ ((r15 >> 1) & 3)) * 8;

    f32x4 acc[4][4];
#pragma unroll
    for (int i = 0; i < 4; i++)
#pragma unroll
        for (int jj = 0; jj < 4; jj++) acc[i][jj] = (f32x4){0.f, 0.f, 0.f, 0.f};

    auto STAGE = [&](int bi, int kt) {
        unsigned short* L = lds + bi * BUF_E;
#pragma unroll
        for (int i = 0; i < 2; i++) {
            int slotbase = i * 256 + wave * 64;
            int slot = slotbase + lane;
            int row = slot >> 2;
            int gc = ((slot & 3) ^ ((row >> 1) & 3));
            int colb = kt + gc * 8;
            // A: reg-stage + bn1+relu transform (bit-identical to a separate convert pass)
            u16x8 y = *reinterpret_cast<const u16x8*>(Yin + (size_t)(m0 + row) * DIM + colb);
            u16x8 h;
#pragma unroll
            for (int jj = 0; jj < 8; jj++)
                h[jj] = f32_to_f16u(fmaxf(f16u_to_f32(y[jj]) * spa[colb + jj] + spc[colb + jj], 0.f));
            *reinterpret_cast<u16x8*>(&L[slot * 8]) = h;
            // B: async direct
            gl_lds16(B + (size_t)(n0 + row) * DIM + colb, L + 4096 + slotbase * 8);
        }
    };

    auto COMPUTE = [&](int bi) {
        unsigned short* L = lds + bi * BUF_E;
        f16x8 bf[4];
#pragma unroll
        for (int nf = 0; nf < 4; nf++) {
            int rb = wn * 64 + nf * 16 + r15;
            bf[nf] = *reinterpret_cast<const f16x8*>(&L[4096 + rb * 32 + rslot]);
        }
#pragma unroll
        for (int mf = 0; mf < 4; mf++) {
            int ra = wm * 64 + mf * 16 + r15;
            f16x8 a = *reinterpret_cast<const f16x8*>(&L[ra * 32 + rslot]);
#pragma unroll
            for (int nf = 0; nf < 4; nf++)
                acc[mf][nf] = __builtin_amdgcn_mfma_f32_16x16x32_f16(a, bf[nf], acc[mf][nf], 0, 0, 0);
        }
    };

    STAGE(0, 0);
    __syncthreads();
    int buf = 0;
#pragma unroll
    for (int t = 0; t < 16; t++) {
        if (t < 15) STAGE(buf ^ 1, (t + 1) * BK);
        COMPUTE(buf);
        __syncthreads();
        buf ^= 1;
    }

    const int ln16 = lane & 15;
    const int lg = lane >> 4;
#pragma unroll
    for (int nf = 0; nf < 4; nf++) {
        int col = n0 + wn * 64 + nf * 16 + ln16;
        float bv = bias[col];
        float s = 0.f, qq = 0.f;
#pragma unroll
        for (int mf = 0; mf < 4; mf++) {
#pragma unroll
            for (int r = 0; r < 4; r++) {
                int row = m0 + wm * 64 + mf * 16 + lg * 4 + r;
                if (row < M) {
                    float v = acc[mf][nf][r] + bv;
                    Yh[(size_t)row * DIM + col] = f32_to_f16u(v);
                    s += v; qq += v * v;
                }
            }
        }
        s += __shfl_xor(s, 16);
        s += __shfl_xor(s, 32);
        qq += __shfl_xor(qq, 16);
        qq += __shfl_xor(qq, 32);
        if (lg == 0) {
            atomicAdd(&ssum[col], s);
            atomicAdd(&ssq[col], qq);
        }
    }
}

// ---------------- ustats (l<2): u = relu(bn2(y2)), in-place U store + st3 ----------
__global__ void ustats_kernel(const unsigned short* __restrict__ Yh,
                              const float* __restrict__ s2sum, const float* __restrict__ s2sq,
                              const float* __restrict__ g2l, const float* __restrict__ be2l,
                              float invN,
                              float* __restrict__ s3sum, float* __restrict__ s3sq,
                              unsigned short* __restrict__ U,
                              int M, int chunk) {
    int d = blockIdx.x * blockDim.x + threadIdx.x;
    float a, c;
    bn_params(s2sum[d], s2sq[d], g2l[d], be2l[d], invN, a, c);
    int r0 = blockIdx.y * chunk;
    int r1 = r0 + chunk; if (r1 > M) r1 = M;
    float s = 0.f, q = 0.f;
    for (int r = r0; r < r1; r++) {
        size_t idx = (size_t)r * DIM + d;
        float v = fmaxf(f16u_to_f32(Yh[idx]) * a + c, 0.f);
        s += v; q += v * v;
        U[idx] = f32_to_f16u(v);
    }
    atomicAdd(&s3sum[d], s);
    atomicAdd(&s3sq[d], q);
}

// ---------------- finalize (+ analytic last-layer BN3 params) ----------------
__global__ void finalize_kernel(const unsigned short* __restrict__ Yh,
                                const float* __restrict__ s2sum, const float* __restrict__ s2sq,
                                const float* __restrict__ g2l, const float* __restrict__ be2l,
                                const float* __restrict__ ngl, const float* __restrict__ nbl,
                                float invN,
                                float* __restrict__ out, int total4) {
    __shared__ float sa2[DIM], sc2[DIM], sa3[DIM], sc3[DIM];
    for (int d = threadIdx.x; d < DIM; d += 256) {
        float a2, c2;
        bn_params(s2sum[d], s2sq[d], g2l[d], be2l[d], invN, a2, c2);
        float m_y = s2sum[d] * invN;
        float var_y = fmaxf(s2sq[d] * invN - m_y * m_y, 0.f);
        float m_u = a2 * m_y + c2;
        float var_u = a2 * a2 * var_y;
        float a3 = ngl[d] * rsqrtf(var_u + BN_EPS);
        float c3 = nbl[d] - m_u * a3;
        sa2[d] = a2; sc2[d] = c2; sa3[d] = a3; sc3[d] = c3;
    }
    __syncthreads();
    int i = blockIdx.x * blockDim.x + threadIdx.x;
    int stride = gridDim.x * blockDim.x;
    for (; i < total4; i += stride) {
        int c = (i & 127) * 4;
        u16x4 y = *reinterpret_cast<const u16x4*>(Yh + (size_t)i * 4);
        f32x4 v;
#pragma unroll
        for (int j = 0; j < 4; j++) {
            float f = f16u_to_f32(y[j]) * sa2[c + j] + sc2[c + j];
            v[j] = f * sa3[c + j] + sc3[c + j];
        }
        *reinterpret_cast<f32x4*>(out + (size_t)i * 4) = v;
    }
}

extern "C" void kernel_launch(void* const* d_in, const int* in_sizes, int n_in,
                              void* d_out, int out_size, void* d_ws, size_t ws_size,
                              hipStream_t stream) {
    const float* x   = (const float*)d_in[0];
    const int*   ei  = (const int*)d_in[1];
    const float* W1  = (const float*)d_in[2];
    const float* b1  = (const float*)d_in[3];
    const float* g1  = (const float*)d_in[4];
    const float* be1 = (const float*)d_in[5];
    const float* W2  = (const float*)d_in[6];
    const float* b2  = (const float*)d_in[7];
    const float* g2  = (const float*)d_in[8];
    const float* be2 = (const float*)d_in[9];
    const float* ng  = (const float*)d_in[10];
    const float* nb  = (const float*)d_in[11];

    const int N = in_sizes[0] / DIM;
    const int E = in_sizes[1] / 2;

    char* ws = (char*)d_ws;
    size_t off = 0;
    auto alloc = [&](size_t bytes) -> void* {
        void* p = ws + off;
        off += (bytes + 255) & ~(size_t)255;
        return p;
    };
    // Rotation: P2 = x-fp16 then y2/U; P0 = agg out (gemm A); P1 = y1.
    unsigned short* P0 = (unsigned short*)alloc((size_t)N * DIM * 2);
    unsigned short* P2 = (unsigned short*)alloc((size_t)N * DIM * 2);
    unsigned short* P1 = (unsigned short*)alloc((size_t)N * DIM * 2);
    unsigned short* Wf = (unsigned short*)alloc(6ull * DIM * DIM * 2);
    int* rowptr = (int*)alloc((size_t)(N + 1) * 4);
    int* counts = (int*)alloc((size_t)N * 4);
    int* cursor = (int*)alloc((size_t)N * 4);
    int* colsrc = (int*)alloc((size_t)E * 4);
    int* bsum   = (int*)alloc(1024 * 4);
    float* stats = (float*)alloc(9ull * 1024 * 4);

    float* Yout = (float*)d_out;

    hipMemsetAsync(counts, 0, (size_t)N * 4, stream);
    hipMemsetAsync(stats, 0, 9ull * 1024 * 4, stream);

    const int NBs = (N + 255) / 256;
    const int total8 = N * DIM / 8;

    prep_kernel<<<1536 + 1024, 256, 0, stream>>>(W1, W2, x, Wf, P2, total8);
    csr_count<<<(E + 255) / 256, 256, 0, stream>>>(ei, counts, E);
    scan1<<<NBs, 256, 0, stream>>>(counts, rowptr, bsum, N);
    scan2<<<1, 256, 0, stream>>>(bsum, NBs);
    scan3<<<NBs, 256, 0, stream>>>(bsum, rowptr, cursor, N, E);
    csr_fill<<<(E + 255) / 256, 256, 0, stream>>>(ei, cursor, colsrc, E);

    const float invN = 1.0f / (float)N;
    const int Gm = (((N + BM - 1) / BM) + 7) & ~7;   // 392 m-panels
    const int gemm_blocks = Gm * 4;
    const int uchunk = (N + 199) / 200;

    for (int l = 0; l < NLAYERS; l++) {
        float* st1 = stats + (size_t)l * 3 * 1024;
        float* st2 = st1 + 1024;
        float* st3 = st2 + 1024;
        if (l == 0)
            agg_b<0><<<N, 128, 0, stream>>>(P2, rowptr, colsrc,
                                            nullptr, nullptr, nullptr, nullptr, invN, P0, N);
        else {
            float* p3 = stats + (size_t)(l - 1) * 3 * 1024 + 2048;
            agg_b<1><<<N, 128, 0, stream>>>(P2, rowptr, colsrc,
                                            p3, p3 + 512, ng + (l - 1) * DIM, nb + (l - 1) * DIM,
                                            invN, P0, N);
        }
        gemm_kernel<<<gemm_blocks, 256, 0, stream>>>(P0,
            Wf + (size_t)(l * 2) * DIM * DIM, b1 + l * DIM, P1, st1, st1 + 512, N);
        gemm2_kernel<<<gemm_blocks, 256, 0, stream>>>(P1,
            st1, st1 + 512, g1 + l * DIM, be1 + l * DIM, invN,
            Wf + (size_t)(l * 2 + 1) * DIM * DIM, b2 + l * DIM, P2, st2, st2 + 512, N);
        if (l < NLAYERS - 1)
            ustats_kernel<<<dim3(2, 200), 256, 0, stream>>>(P2, st2, st2 + 512,
                                                            g2 + l * DIM, be2 + l * DIM, invN,
                                                            st3, st3 + 512, P2, N, uchunk);
    }
    {
        int l = NLAYERS - 1;
        float* st2 = stats + (size_t)l * 3 * 1024 + 1024;
        finalize_kernel<<<2048, 256, 0, stream>>>(P2, st2, st2 + 512,
                                                  g2 + l * DIM, be2 + l * DIM,
                                                  ng + l * DIM, nb + l * DIM, invN,
                                                  Yout, N * DIM / 4);
    }
}

// Round 20
// 1127.202 us; speedup vs baseline: 1.1435x; 1.0036x over previous
//
#include <hip/hip_runtime.h>
#include <cstdint>
#include <cstddef>

#define DIM 512
#define NLAYERS 3
#define BM 128
#define BN 128
#define BK 32
#define BUF_E 8192    // elems per buffer: A 4096 + B 4096 (16 KB)
#define BN_EPS 1e-5f

typedef float f32x4 __attribute__((ext_vector_type(4)));
typedef _Float16 f16x8 __attribute__((ext_vector_type(8)));
typedef unsigned short u16x4 __attribute__((ext_vector_type(4)));
typedef unsigned short u16x8 __attribute__((ext_vector_type(8)));

__device__ __forceinline__ unsigned short f32_to_f16u(float f) {
    _Float16 h = (_Float16)f;
    return __builtin_bit_cast(unsigned short, h);
}
__device__ __forceinline__ float f16u_to_f32(unsigned short u) {
    return (float)__builtin_bit_cast(_Float16, u);
}

__device__ __forceinline__ void gl_lds16(const unsigned short* g, unsigned short* l) {
    __builtin_amdgcn_global_load_lds(
        (const __attribute__((address_space(1))) void*)g,
        (__attribute__((address_space(3))) void*)l,
        16, 0, 0);
}

__device__ __forceinline__ void bn_params(float ssum, float ssq, float g, float b,
                                          float invN, float& a, float& c) {
    float m = ssum * invN;
    float var = fmaxf(ssq * invN - m * m, 0.f);
    a = g * rsqrtf(var + BN_EPS);
    c = b - m * a;
}

// ---------------- CSR build ----------------
__global__ void csr_count(const int* __restrict__ ei, int* __restrict__ counts, int E) {
    int e = blockIdx.x * 256 + threadIdx.x;
    if (e < E) atomicAdd(&counts[ei[E + e]], 1);
}

__global__ void scan1(const int* __restrict__ counts, int* __restrict__ rowptr,
                      int* __restrict__ bsum, int N) {
    __shared__ int sh[256];
    int t = threadIdx.x;
    int i = blockIdx.x * 256 + t;
    int v = (i < N) ? counts[i] : 0;
    sh[t] = v;
    __syncthreads();
    for (int d = 1; d < 256; d <<= 1) {
        int u = (t >= d) ? sh[t - d] : 0;
        __syncthreads();
        sh[t] += u;
        __syncthreads();
    }
    if (i < N) rowptr[i] = sh[t] - v;
    if (t == 255) bsum[blockIdx.x] = sh[255];
}

__global__ void scan2(int* __restrict__ bsum, int NB) {
    __shared__ int sh[256];
    int t = threadIdx.x;
    int v = (t < NB) ? bsum[t] : 0;
    sh[t] = v;
    __syncthreads();
    for (int d = 1; d < 256; d <<= 1) {
        int u = (t >= d) ? sh[t - d] : 0;
        __syncthreads();
        sh[t] += u;
        __syncthreads();
    }
    if (t < NB) bsum[t] = sh[t] - v;
}

__global__ void scan3(const int* __restrict__ bsum, int* __restrict__ rowptr,
                      int* __restrict__ cursor, int N, int E) {
    int i = blockIdx.x * 256 + threadIdx.x;
    if (i < N) {
        int v = rowptr[i] + bsum[blockIdx.x];
        rowptr[i] = v;
        cursor[i] = v;
    }
    if (blockIdx.x == 0 && threadIdx.x == 0) rowptr[N] = E;
}

__global__ void csr_fill(const int* __restrict__ ei, int* __restrict__ cursor,
                         int* __restrict__ colsrc, int E) {
    int e = blockIdx.x * 256 + threadIdx.x;
    if (e < E) {
        int s = ei[e], d = ei[E + e];
        int p = atomicAdd(&cursor[d], 1);
        colsrc[p] = s;
    }
}

// ---------------- fused prep: blocks <1536 -> W fp16 transpose; rest -> x fp16 ----------
__global__ void prep_kernel(const float* __restrict__ W1, const float* __restrict__ W2,
                            const float* __restrict__ X,
                            unsigned short* __restrict__ Wf,
                            unsigned short* __restrict__ Xh, int total8) {
    if (blockIdx.x < 1536) {
        int id = blockIdx.x * 256 + threadIdx.x;
        int mat = id >> 16;
        int k4 = (id >> 9) & 127;
        int n = id & 511;
        const float* W = (mat & 1) ? W2 : W1;
        const float* base = W + (size_t)(mat >> 1) * DIM * DIM;
        u16x4 h;
#pragma unroll
        for (int j = 0; j < 4; j++)
            h[j] = f32_to_f16u(base[(size_t)(k4 * 4 + j) * DIM + n]);
        size_t o = ((size_t)mat * DIM + n) * DIM + k4 * 4;
        *reinterpret_cast<u16x4*>(Wf + o) = h;
    } else {
        int i = (blockIdx.x - 1536) * 256 + threadIdx.x;
        int stride = (gridDim.x - 1536) * 256;
        for (; i < total8; i += stride) {
            f32x4 v0 = *reinterpret_cast<const f32x4*>(X + (size_t)i * 8);
            f32x4 v1 = *reinterpret_cast<const f32x4*>(X + (size_t)i * 8 + 4);
            u16x8 h;
#pragma unroll
            for (int j = 0; j < 4; j++) h[j] = f32_to_f16u(v0[j]);
#pragma unroll
            for (int j = 0; j < 4; j++) h[4 + j] = f32_to_f16u(v1[j]);
            __builtin_nontemporal_store(h, reinterpret_cast<u16x8*>(Xh + (size_t)i * 8));
        }
    }
}

// ---------------- aggregation over fp16 rows -> fp16 A-plane ----------------
// MODE 0: T = identity (layer 0, U = f16(x)).
// MODE 1: T(y) = relu(relu(y*a2+c2)*a3+c3) — bn2+relu+bn3+relu folded (params from
// st2/st3 of the previous layer; no intermediate fp16 rounding of u).
template<int MODE>
__global__ void agg_b(const unsigned short* __restrict__ U,
                      const int* __restrict__ rowptr, const int* __restrict__ colsrc,
                      const float* __restrict__ s2sum, const float* __restrict__ s2sq,
                      const float* __restrict__ g2l, const float* __restrict__ be2l,
                      const float* __restrict__ s3sum, const float* __restrict__ s3sq,
                      const float* __restrict__ ngl, const float* __restrict__ nbl,
                      float invN,
                      unsigned short* __restrict__ Phi, int N) {
    int n = blockIdx.x;
    int c = threadIdx.x * 4;
    f32x4 a2, c2, a3, c3;
    if (MODE) {
#pragma unroll
        for (int j = 0; j < 4; j++) {
            float a, cc;
            bn_params(s2sum[c + j], s2sq[c + j], g2l[c + j], be2l[c + j], invN, a, cc);
            a2[j] = a; c2[j] = cc;
            bn_params(s3sum[c + j], s3sq[c + j], ngl[c + j], nbl[c + j], invN, a, cc);
            a3[j] = a; c3[j] = cc;
        }
    }
    auto ldT = [&](int r) -> f32x4 {
        u16x4 u = *reinterpret_cast<const u16x4*>(U + (size_t)r * DIM + c);
        f32x4 v;
#pragma unroll
        for (int j = 0; j < 4; j++) {
            float f = f16u_to_f32(u[j]);
            if (MODE) {
                f = fmaxf(f * a2[j] + c2[j], 0.f);
                f = fmaxf(f * a3[j] + c3[j], 0.f);
            }
            v[j] = f;
        }
        return v;
    };
    f32x4 acc = ldT(n);
    int e0 = rowptr[n], e1 = rowptr[n + 1];
    int e = e0;
    for (; e + 8 <= e1; e += 8) {
        int s0 = colsrc[e],     s1 = colsrc[e + 1], s2 = colsrc[e + 2], s3 = colsrc[e + 3];
        int s4 = colsrc[e + 4], s5 = colsrc[e + 5], s6 = colsrc[e + 6], s7 = colsrc[e + 7];
        f32x4 v0 = ldT(s0);
        f32x4 v1 = ldT(s1);
        f32x4 v2 = ldT(s2);
        f32x4 v3 = ldT(s3);
        f32x4 v4 = ldT(s4);
        f32x4 v5 = ldT(s5);
        f32x4 v6 = ldT(s6);
        f32x4 v7 = ldT(s7);
        acc += v0; acc += v1; acc += v2; acc += v3;
        acc += v4; acc += v5; acc += v6; acc += v7;
    }
    for (; e < e1; e++) acc += ldT(colsrc[e]);
    u16x4 h;
#pragma unroll
    for (int j = 0; j < 4; j++) h[j] = f32_to_f16u(acc[j]);
    *reinterpret_cast<u16x4*>(Phi + (size_t)n * DIM + c) = h;
}

// ---------------- GEMM1: fp16 single-plane, 128x128, BK=32, dbuf ----------
__global__ __launch_bounds__(256, 4)
void gemm_kernel(const unsigned short* __restrict__ A,
                 const unsigned short* __restrict__ B,
                 const float* __restrict__ bias,
                 unsigned short* __restrict__ Yh,
                 float* __restrict__ ssum, float* __restrict__ ssq,
                 int M) {
    __shared__ unsigned short lds[2 * BUF_E];   // 32 KB

    const int tid = threadIdx.x;
    const int lane = tid & 63;
    const int wave = tid >> 6;
    const int wm = wave >> 1, wn = wave & 1;

    const int b = blockIdx.x;
    const int xcd = b & 7;
    const int slot_ = b >> 3;
    const int g = (slot_ >> 2) * 8 + xcd;
    const int j = slot_ & 3;
    const int m0 = g * BM;
    const int n0 = j * BN;

    const int r15 = lane & 15;
    const int rslot = ((lane >> 4) ^ ((r15 >> 1) & 3)) * 8;

    f32x4 acc[4][4];
#pragma unroll
    for (int i = 0; i < 4; i++)
#pragma unroll
        for (int jj = 0; jj < 4; jj++) acc[i][jj] = (f32x4){0.f, 0.f, 0.f, 0.f};

    auto STAGE = [&](int bi, int kt) {
        unsigned short* L = lds + bi * BUF_E;
#pragma unroll
        for (int i = 0; i < 2; i++) {
            int slotbase = i * 256 + wave * 64;
            int slot = slotbase + lane;
            int row = slot >> 2;
            int gc = ((slot & 3) ^ ((row >> 1) & 3)) * 8;
            gl_lds16(A + (size_t)(m0 + row) * DIM + kt + gc, L + slotbase * 8);
            gl_lds16(B + (size_t)(n0 + row) * DIM + kt + gc, L + 4096 + slotbase * 8);
        }
    };

    auto COMPUTE = [&](int bi) {
        unsigned short* L = lds + bi * BUF_E;
        f16x8 bf[4];
#pragma unroll
        for (int nf = 0; nf < 4; nf++) {
            int rb = wn * 64 + nf * 16 + r15;
            bf[nf] = *reinterpret_cast<const f16x8*>(&L[4096 + rb * 32 + rslot]);
        }
#pragma unroll
        for (int mf = 0; mf < 4; mf++) {
            int ra = wm * 64 + mf * 16 + r15;
            f16x8 a = *reinterpret_cast<const f16x8*>(&L[ra * 32 + rslot]);
#pragma unroll
            for (int nf = 0; nf < 4; nf++)
                acc[mf][nf] = __builtin_amdgcn_mfma_f32_16x16x32_f16(a, bf[nf], acc[mf][nf], 0, 0, 0);
        }
    };

    STAGE(0, 0);
    __syncthreads();
    int buf = 0;
#pragma unroll
    for (int t = 0; t < 16; t++) {
        if (t < 15) STAGE(buf ^ 1, (t + 1) * BK);
        COMPUTE(buf);
        __syncthreads();
        buf ^= 1;
    }

    const int ln16 = lane & 15;
    const int lg = lane >> 4;
#pragma unroll
    for (int nf = 0; nf < 4; nf++) {
        int col = n0 + wn * 64 + nf * 16 + ln16;
        float bv = bias[col];
        float s = 0.f, qq = 0.f;
#pragma unroll
        for (int mf = 0; mf < 4; mf++) {
#pragma unroll
            for (int r = 0; r < 4; r++) {
                int row = m0 + wm * 64 + mf * 16 + lg * 4 + r;
                if (row < M) {
                    float v = acc[mf][nf][r] + bv;
                    Yh[(size_t)row * DIM + col] = f32_to_f16u(v);
                    s += v; qq += v * v;
                }
            }
        }
        s += __shfl_xor(s, 16);
        s += __shfl_xor(s, 32);
        qq += __shfl_xor(qq, 16);
        qq += __shfl_xor(qq, 32);
        if (lg == 0) {
            atomicAdd(&ssum[col], s);
            atomicAdd(&ssq[col], qq);
        }
    }
}

// ---------------- GEMM2: A = f16(relu(bn1(y1))) fused in staging; B via gl_lds ----------
__global__ __launch_bounds__(256, 4)
void gemm2_kernel(const unsigned short* __restrict__ Yin,
                  const float* __restrict__ s1sum, const float* __restrict__ s1sq,
                  const float* __restrict__ g1l, const float* __restrict__ be1l,
                  float invN,
                  const unsigned short* __restrict__ B,
                  const float* __restrict__ bias,
                  unsigned short* __restrict__ Yh,
                  float* __restrict__ ssum, float* __restrict__ ssq,
                  int M) {
    __shared__ unsigned short lds[2 * BUF_E];   // 32 KB
    __shared__ float spa[DIM], spc[DIM];        // +4 KB

    const int tid = threadIdx.x;
    const int lane = tid & 63;
    const int wave = tid >> 6;
    const int wm = wave >> 1, wn = wave & 1;

    for (int d = tid; d < DIM; d += 256) {
        float a, c;
        bn_params(s1sum[d], s1sq[d], g1l[d], be1l[d], invN, a, c);
        spa[d] = a; spc[d] = c;
    }
    __syncthreads();

    const int b = blockIdx.x;
    const int xcd = b & 7;
    const int slot_ = b >> 3;
    const int g = (slot_ >> 2) * 8 + xcd;
    const int j = slot_ & 3;
    const int m0 = g * BM;
    const int n0 = j * BN;

    const int r15 = lane & 15;
    const int rslot = ((lane >> 4) ^ ((r15 >> 1) & 3)) * 8;

    f32x4 acc[4][4];
#pragma unroll
    for (int i = 0; i < 4; i++)
#pragma unroll
        for (int jj = 0; jj < 4; jj++) acc[i][jj] = (f32x4){0.f, 0.f, 0.f, 0.f};

    auto STAGE = [&](int bi, int kt) {
        unsigned short* L = lds + bi * BUF_E;
#pragma unroll
        for (int i = 0; i < 2; i++) {
            int slotbase = i * 256 + wave * 64;
            int slot = slotbase + lane;
            int row = slot >> 2;
            int gc = ((slot & 3) ^ ((row >> 1) & 3));
            int colb = kt + gc * 8;
            u16x8 y = *reinterpret_cast<const u16x8*>(Yin + (size_t)(m0 + row) * DIM + colb);
            u16x8 h;
#pragma unroll
            for (int jj = 0; jj < 8; jj++)
                h[jj] = f32_to_f16u(fmaxf(f16u_to_f32(y[jj]) * spa[colb + jj] + spc[colb + jj], 0.f));
            *reinterpret_cast<u16x8*>(&L[slot * 8]) = h;
            gl_lds16(B + (size_t)(n0 + row) * DIM + colb, L + 4096 + slotbase * 8);
        }
    };

    auto COMPUTE = [&](int bi) {
        unsigned short* L = lds + bi * BUF_E;
        f16x8 bf[4];
#pragma unroll
        for (int nf = 0; nf < 4; nf++) {
            int rb = wn * 64 + nf * 16 + r15;
            bf[nf] = *reinterpret_cast<const f16x8*>(&L[4096 + rb * 32 + rslot]);
        }
#pragma unroll
        for (int mf = 0; mf < 4; mf++) {
            int ra = wm * 64 + mf * 16 + r15;
            f16x8 a = *reinterpret_cast<const f16x8*>(&L[ra * 32 + rslot]);
#pragma unroll
            for (int nf = 0; nf < 4; nf++)
                acc[mf][nf] = __builtin_amdgcn_mfma_f32_16x16x32_f16(a, bf[nf], acc[mf][nf], 0, 0, 0);
        }
    };

    STAGE(0, 0);
    __syncthreads();
    int buf = 0;
#pragma unroll
    for (int t = 0; t < 16; t++) {
        if (t < 15) STAGE(buf ^ 1, (t + 1) * BK);
        COMPUTE(buf);
        __syncthreads();
        buf ^= 1;
    }

    const int ln16 = lane & 15;
    const int lg = lane >> 4;
#pragma unroll
    for (int nf = 0; nf < 4; nf++) {
        int col = n0 + wn * 64 + nf * 16 + ln16;
        float bv = bias[col];
        float s = 0.f, qq = 0.f;
#pragma unroll
        for (int mf = 0; mf < 4; mf++) {
#pragma unroll
            for (int r = 0; r < 4; r++) {
                int row = m0 + wm * 64 + mf * 16 + lg * 4 + r;
                if (row < M) {
                    float v = acc[mf][nf][r] + bv;
                    Yh[(size_t)row * DIM + col] = f32_to_f16u(v);
                    s += v; qq += v * v;
                }
            }
        }
        s += __shfl_xor(s, 16);
        s += __shfl_xor(s, 32);
        qq += __shfl_xor(qq, 16);
        qq += __shfl_xor(qq, 32);
        if (lg == 0) {
            atomicAdd(&ssum[col], s);
            atomicAdd(&ssq[col], qq);
        }
    }
}

// ---------------- ustats (l<2): STATS-ONLY pass over u = relu(bn2(y2)) ----------
__global__ void ustats_kernel(const unsigned short* __restrict__ Yh,
                              const float* __restrict__ s2sum, const float* __restrict__ s2sq,
                              const float* __restrict__ g2l, const float* __restrict__ be2l,
                              float invN,
                              float* __restrict__ s3sum, float* __restrict__ s3sq,
                              int M, int chunk) {
    int d = blockIdx.x * blockDim.x + threadIdx.x;
    float a, c;
    bn_params(s2sum[d], s2sq[d], g2l[d], be2l[d], invN, a, c);
    int r0 = blockIdx.y * chunk;
    int r1 = r0 + chunk; if (r1 > M) r1 = M;
    float s = 0.f, q = 0.f;
    for (int r = r0; r < r1; r++) {
        float v = fmaxf(f16u_to_f32(Yh[(size_t)r * DIM + d]) * a + c, 0.f);
        s += v; q += v * v;
    }
    atomicAdd(&s3sum[d], s);
    atomicAdd(&s3sq[d], q);
}

// ---------------- finalize (+ analytic last-layer BN3 params) ----------------
__global__ void finalize_kernel(const unsigned short* __restrict__ Yh,
                                const float* __restrict__ s2sum, const float* __restrict__ s2sq,
                                const float* __restrict__ g2l, const float* __restrict__ be2l,
                                const float* __restrict__ ngl, const float* __restrict__ nbl,
                                float invN,
                                float* __restrict__ out, int total4) {
    __shared__ float sa2[DIM], sc2[DIM], sa3[DIM], sc3[DIM];
    for (int d = threadIdx.x; d < DIM; d += 256) {
        float a2, c2;
        bn_params(s2sum[d], s2sq[d], g2l[d], be2l[d], invN, a2, c2);
        float m_y = s2sum[d] * invN;
        float var_y = fmaxf(s2sq[d] * invN - m_y * m_y, 0.f);
        float m_u = a2 * m_y + c2;
        float var_u = a2 * a2 * var_y;
        float a3 = ngl[d] * rsqrtf(var_u + BN_EPS);
        float c3 = nbl[d] - m_u * a3;
        sa2[d] = a2; sc2[d] = c2; sa3[d] = a3; sc3[d] = c3;
    }
    __syncthreads();
    int i = blockIdx.x * blockDim.x + threadIdx.x;
    int stride = gridDim.x * blockDim.x;
    for (; i < total4; i += stride) {
        int c = (i & 127) * 4;
        u16x4 y = *reinterpret_cast<const u16x4*>(Yh + (size_t)i * 4);
        f32x4 v;
#pragma unroll
        for (int j = 0; j < 4; j++) {
            float f = f16u_to_f32(y[j]) * sa2[c + j] + sc2[c + j];
            v[j] = f * sa3[c + j] + sc3[c + j];
        }
        *reinterpret_cast<f32x4*>(out + (size_t)i * 4) = v;
    }
}

extern "C" void kernel_launch(void* const* d_in, const int* in_sizes, int n_in,
                              void* d_out, int out_size, void* d_ws, size_t ws_size,
                              hipStream_t stream) {
    const float* x   = (const float*)d_in[0];
    const int*   ei  = (const int*)d_in[1];
    const float* W1  = (const float*)d_in[2];
    const float* b1  = (const float*)d_in[3];
    const float* g1  = (const float*)d_in[4];
    const float* be1 = (const float*)d_in[5];
    const float* W2  = (const float*)d_in[6];
    const float* b2  = (const float*)d_in[7];
    const float* g2  = (const float*)d_in[8];
    const float* be2 = (const float*)d_in[9];
    const float* ng  = (const float*)d_in[10];
    const float* nb  = (const float*)d_in[11];

    const int N = in_sizes[0] / DIM;
    const int E = in_sizes[1] / 2;

    char* ws = (char*)d_ws;
    size_t off = 0;
    auto alloc = [&](size_t bytes) -> void* {
        void* p = ws + off;
        off += (bytes + 255) & ~(size_t)255;
        return p;
    };
    // Rotation: P2 = x-fp16 then y2; P0 = agg out (gemm A); P1 = y1.
    unsigned short* P0 = (unsigned short*)alloc((size_t)N * DIM * 2);
    unsigned short* P2 = (unsigned short*)alloc((size_t)N * DIM * 2);
    unsigned short* P1 = (unsigned short*)alloc((size_t)N * DIM * 2);
    unsigned short* Wf = (unsigned short*)alloc(6ull * DIM * DIM * 2);
    int* rowptr = (int*)alloc((size_t)(N + 1) * 4);
    int* counts = (int*)alloc((size_t)N * 4);
    int* cursor = (int*)alloc((size_t)N * 4);
    int* colsrc = (int*)alloc((size_t)E * 4);
    int* bsum   = (int*)alloc(1024 * 4);
    float* stats = (float*)alloc(9ull * 1024 * 4);

    float* Yout = (float*)d_out;

    hipMemsetAsync(counts, 0, (size_t)N * 4, stream);
    hipMemsetAsync(stats, 0, 9ull * 1024 * 4, stream);

    const int NBs = (N + 255) / 256;
    const int total8 = N * DIM / 8;

    prep_kernel<<<1536 + 1024, 256, 0, stream>>>(W1, W2, x, Wf, P2, total8);
    csr_count<<<(E + 255) / 256, 256, 0, stream>>>(ei, counts, E);
    scan1<<<NBs, 256, 0, stream>>>(counts, rowptr, bsum, N);
    scan2<<<1, 256, 0, stream>>>(bsum, NBs);
    scan3<<<NBs, 256, 0, stream>>>(bsum, rowptr, cursor, N, E);
    csr_fill<<<(E + 255) / 256, 256, 0, stream>>>(ei, cursor, colsrc, E);

    const float invN = 1.0f / (float)N;
    const int Gm = (((N + BM - 1) / BM) + 7) & ~7;   // 392 m-panels
    const int gemm_blocks = Gm * 4;
    const int uchunk = (N + 199) / 200;

    for (int l = 0; l < NLAYERS; l++) {
        float* st1 = stats + (size_t)l * 3 * 1024;
        float* st2 = st1 + 1024;
        float* st3 = st2 + 1024;
        if (l == 0)
            agg_b<0><<<N, 128, 0, stream>>>(P2, rowptr, colsrc,
                                            nullptr, nullptr, nullptr, nullptr,
                                            nullptr, nullptr, nullptr, nullptr,
                                            invN, P0, N);
        else {
            float* p2s = stats + (size_t)(l - 1) * 3 * 1024 + 1024;   // prev st2
            float* p3s = p2s + 1024;                                   // prev st3
            agg_b<1><<<N, 128, 0, stream>>>(P2, rowptr, colsrc,
                                            p2s, p2s + 512, g2 + (l - 1) * DIM, be2 + (l - 1) * DIM,
                                            p3s, p3s + 512, ng + (l - 1) * DIM, nb + (l - 1) * DIM,
                                            invN, P0, N);
        }
        gemm_kernel<<<gemm_blocks, 256, 0, stream>>>(P0,
            Wf + (size_t)(l * 2) * DIM * DIM, b1 + l * DIM, P1, st1, st1 + 512, N);
        gemm2_kernel<<<gemm_blocks, 256, 0, stream>>>(P1,
            st1, st1 + 512, g1 + l * DIM, be1 + l * DIM, invN,
            Wf + (size_t)(l * 2 + 1) * DIM * DIM, b2 + l * DIM, P2, st2, st2 + 512, N);
        if (l < NLAYERS - 1)
            ustats_kernel<<<dim3(2, 200), 256, 0, stream>>>(P2, st2, st2 + 512,
                                                            g2 + l * DIM, be2 + l * DIM, invN,
                                                            st3, st3 + 512, N, uchunk);
    }
    {
        int l = NLAYERS - 1;
        float* st2 = stats + (size_t)l * 3 * 1024 + 1024;
        finalize_kernel<<<2048, 256, 0, stream>>>(P2, st2, st2 + 512,
                                                  g2 + l * DIM, be2 + l * DIM,
                                                  ng + l * DIM, nb + l * DIM, invN,
                                                  Yout, N * DIM / 4);
    }
}

// Round 21
// 1085.874 us; speedup vs baseline: 1.1870x; 1.0381x over previous
//
#include <hip/hip_runtime.h>
#include <cstdint>
#include <cstddef>

#define DIM 512
#define NLAYERS 3
#define BM 128
#define BN 128
#define BK 32
#define BUF_E 8192    // elems per buffer: A 4096 + B 4096 (16 KB)
#define BN_EPS 1e-5f
#define PREP_W 1536
#define PREP_X 1024
#define PREP_C 784

typedef float f32x4 __attribute__((ext_vector_type(4)));
typedef _Float16 f16x8 __attribute__((ext_vector_type(8)));
typedef unsigned short u16x4 __attribute__((ext_vector_type(4)));
typedef unsigned short u16x8 __attribute__((ext_vector_type(8)));

__device__ __forceinline__ unsigned short f32_to_f16u(float f) {
    _Float16 h = (_Float16)f;
    return __builtin_bit_cast(unsigned short, h);
}
__device__ __forceinline__ float f16u_to_f32(unsigned short u) {
    return (float)__builtin_bit_cast(_Float16, u);
}

__device__ __forceinline__ void gl_lds16(const unsigned short* g, unsigned short* l) {
    __builtin_amdgcn_global_load_lds(
        (const __attribute__((address_space(1))) void*)g,
        (__attribute__((address_space(3))) void*)l,
        16, 0, 0);
}

__device__ __forceinline__ void bn_params(float ssum, float ssq, float g, float b,
                                          float invN, float& a, float& c) {
    float m = ssum * invN;
    float var = fmaxf(ssq * invN - m * m, 0.f);
    a = g * rsqrtf(var + BN_EPS);
    c = b - m * a;
}

// ---------------- fused prep: W->fp16T | x->fp16 | csr_count | stats zero ----------------
// counts is zeroed by a preceding memsetAsync (stream-ordered before this kernel).
__global__ void prep_kernel(const float* __restrict__ W1, const float* __restrict__ W2,
                            const float* __restrict__ X, const int* __restrict__ ei,
                            unsigned short* __restrict__ Wf, unsigned short* __restrict__ Xh,
                            int* __restrict__ counts, float* __restrict__ stats,
                            int total8, int E) {
    int blk = blockIdx.x;
    if (blk < PREP_W) {
        int id = blk * 256 + threadIdx.x;
        int mat = id >> 16;
        int k4 = (id >> 9) & 127;
        int n = id & 511;
        const float* W = (mat & 1) ? W2 : W1;
        const float* base = W + (size_t)(mat >> 1) * DIM * DIM;
        u16x4 h;
#pragma unroll
        for (int j = 0; j < 4; j++)
            h[j] = f32_to_f16u(base[(size_t)(k4 * 4 + j) * DIM + n]);
        size_t o = ((size_t)mat * DIM + n) * DIM + k4 * 4;
        *reinterpret_cast<u16x4*>(Wf + o) = h;
    } else if (blk < PREP_W + PREP_X) {
        int i = (blk - PREP_W) * 256 + threadIdx.x;
        int stride = PREP_X * 256;
        for (; i < total8; i += stride) {
            f32x4 v0 = *reinterpret_cast<const f32x4*>(X + (size_t)i * 8);
            f32x4 v1 = *reinterpret_cast<const f32x4*>(X + (size_t)i * 8 + 4);
            u16x8 h;
#pragma unroll
            for (int j = 0; j < 4; j++) h[j] = f32_to_f16u(v0[j]);
#pragma unroll
            for (int j = 0; j < 4; j++) h[4 + j] = f32_to_f16u(v1[j]);
            __builtin_nontemporal_store(h, reinterpret_cast<u16x8*>(Xh + (size_t)i * 8));
        }
    } else if (blk < PREP_W + PREP_X + PREP_C) {
        int i = (blk - PREP_W - PREP_X) * 256 + threadIdx.x;
        int stride = PREP_C * 256;
        for (; i < E; i += stride) atomicAdd(&counts[ei[E + i]], 1);
    } else {
        for (int i = threadIdx.x; i < 9 * 1024; i += 256) stats[i] = 0.f;
    }
}

// ---------------- CSR scan (2 dispatches) ----------------
__global__ void scan1(const int* __restrict__ counts, int* __restrict__ rowptr,
                      int* __restrict__ bsum, int N) {
    __shared__ int sh[256];
    int t = threadIdx.x;
    int i = blockIdx.x * 256 + t;
    int v = (i < N) ? counts[i] : 0;
    sh[t] = v;
    __syncthreads();
    for (int d = 1; d < 256; d <<= 1) {
        int u = (t >= d) ? sh[t - d] : 0;
        __syncthreads();
        sh[t] += u;
        __syncthreads();
    }
    if (i < N) rowptr[i] = sh[t] - v;
    if (t == 255) bsum[blockIdx.x] = sh[255];
}

// scan3b: each block reduces bsum[0..bid) itself (NBs <= 256), then applies offset.
__global__ void scan3b(const int* __restrict__ bsum, int* __restrict__ rowptr,
                       int* __restrict__ cursor, int N, int E) {
    __shared__ int sh[256];
    int t = threadIdx.x;
    int bid = blockIdx.x;
    sh[t] = (t < bid) ? bsum[t] : 0;
    __syncthreads();
    for (int d = 128; d > 0; d >>= 1) {
        if (t < d) sh[t] += sh[t + d];
        __syncthreads();
    }
    int off = sh[0];
    int i = bid * 256 + t;
    if (i < N) {
        int r = rowptr[i] + off;
        rowptr[i] = r;
        cursor[i] = r;
    }
    if (bid == 0 && t == 0) rowptr[N] = E;
}

__global__ void csr_fill(const int* __restrict__ ei, int* __restrict__ cursor,
                         int* __restrict__ colsrc, int E) {
    int e = blockIdx.x * 256 + threadIdx.x;
    if (e < E) {
        int s = ei[e], d = ei[E + e];
        int p = atomicAdd(&cursor[d], 1);
        colsrc[p] = s;
    }
}

// ---------------- aggregation over fp16 rows -> fp16 A-plane ----------------
// MODE 0: T = identity (layer 0, U = f16(x)).
// MODE 1: T(y) = relu(relu(y*a2+c2)*a3+c3) — bn2+relu+bn3+relu folded.
template<int MODE>
__global__ void agg_b(const unsigned short* __restrict__ U,
                      const int* __restrict__ rowptr, const int* __restrict__ colsrc,
                      const float* __restrict__ s2sum, const float* __restrict__ s2sq,
                      const float* __restrict__ g2l, const float* __restrict__ be2l,
                      const float* __restrict__ s3sum, const float* __restrict__ s3sq,
                      const float* __restrict__ ngl, const float* __restrict__ nbl,
                      float invN,
                      unsigned short* __restrict__ Phi, int N) {
    int n = blockIdx.x;
    int c = threadIdx.x * 4;
    f32x4 a2, c2, a3, c3;
    if (MODE) {
#pragma unroll
        for (int j = 0; j < 4; j++) {
            float a, cc;
            bn_params(s2sum[c + j], s2sq[c + j], g2l[c + j], be2l[c + j], invN, a, cc);
            a2[j] = a; c2[j] = cc;
            bn_params(s3sum[c + j], s3sq[c + j], ngl[c + j], nbl[c + j], invN, a, cc);
            a3[j] = a; c3[j] = cc;
        }
    }
    auto ldT = [&](int r) -> f32x4 {
        u16x4 u = *reinterpret_cast<const u16x4*>(U + (size_t)r * DIM + c);
        f32x4 v;
#pragma unroll
        for (int j = 0; j < 4; j++) {
            float f = f16u_to_f32(u[j]);
            if (MODE) {
                f = fmaxf(f * a2[j] + c2[j], 0.f);
                f = fmaxf(f * a3[j] + c3[j], 0.f);
            }
            v[j] = f;
        }
        return v;
    };
    f32x4 acc = ldT(n);
    int e0 = rowptr[n], e1 = rowptr[n + 1];
    int e = e0;
    for (; e + 8 <= e1; e += 8) {
        int s0 = colsrc[e],     s1 = colsrc[e + 1], s2 = colsrc[e + 2], s3 = colsrc[e + 3];
        int s4 = colsrc[e + 4], s5 = colsrc[e + 5], s6 = colsrc[e + 6], s7 = colsrc[e + 7];
        f32x4 v0 = ldT(s0);
        f32x4 v1 = ldT(s1);
        f32x4 v2 = ldT(s2);
        f32x4 v3 = ldT(s3);
        f32x4 v4 = ldT(s4);
        f32x4 v5 = ldT(s5);
        f32x4 v6 = ldT(s6);
        f32x4 v7 = ldT(s7);
        acc += v0; acc += v1; acc += v2; acc += v3;
        acc += v4; acc += v5; acc += v6; acc += v7;
    }
    for (; e < e1; e++) acc += ldT(colsrc[e]);
    u16x4 h;
#pragma unroll
    for (int j = 0; j < 4; j++) h[j] = f32_to_f16u(acc[j]);
    *reinterpret_cast<u16x4*>(Phi + (size_t)n * DIM + c) = h;
}

// ---------------- GEMM1: fp16 single-plane, 128x128, BK=32, dbuf ----------
__global__ __launch_bounds__(256, 4)
void gemm_kernel(const unsigned short* __restrict__ A,
                 const unsigned short* __restrict__ B,
                 const float* __restrict__ bias,
                 unsigned short* __restrict__ Yh,
                 float* __restrict__ ssum, float* __restrict__ ssq,
                 int M) {
    __shared__ unsigned short lds[2 * BUF_E];   // 32 KB

    const int tid = threadIdx.x;
    const int lane = tid & 63;
    const int wave = tid >> 6;
    const int wm = wave >> 1, wn = wave & 1;

    const int b = blockIdx.x;
    const int xcd = b & 7;
    const int slot_ = b >> 3;
    const int g = (slot_ >> 2) * 8 + xcd;
    const int j = slot_ & 3;
    const int m0 = g * BM;
    const int n0 = j * BN;

    const int r15 = lane & 15;
    const int rslot = ((lane >> 4) ^ ((r15 >> 1) & 3)) * 8;

    f32x4 acc[4][4];
#pragma unroll
    for (int i = 0; i < 4; i++)
#pragma unroll
        for (int jj = 0; jj < 4; jj++) acc[i][jj] = (f32x4){0.f, 0.f, 0.f, 0.f};

    auto STAGE = [&](int bi, int kt) {
        unsigned short* L = lds + bi * BUF_E;
#pragma unroll
        for (int i = 0; i < 2; i++) {
            int slotbase = i * 256 + wave * 64;
            int slot = slotbase + lane;
            int row = slot >> 2;
            int gc = ((slot & 3) ^ ((row >> 1) & 3)) * 8;
            gl_lds16(A + (size_t)(m0 + row) * DIM + kt + gc, L + slotbase * 8);
            gl_lds16(B + (size_t)(n0 + row) * DIM + kt + gc, L + 4096 + slotbase * 8);
        }
    };

    auto COMPUTE = [&](int bi) {
        unsigned short* L = lds + bi * BUF_E;
        f16x8 bf[4];
#pragma unroll
        for (int nf = 0; nf < 4; nf++) {
            int rb = wn * 64 + nf * 16 + r15;
            bf[nf] = *reinterpret_cast<const f16x8*>(&L[4096 + rb * 32 + rslot]);
        }
#pragma unroll
        for (int mf = 0; mf < 4; mf++) {
            int ra = wm * 64 + mf * 16 + r15;
            f16x8 a = *reinterpret_cast<const f16x8*>(&L[ra * 32 + rslot]);
#pragma unroll
            for (int nf = 0; nf < 4; nf++)
                acc[mf][nf] = __builtin_amdgcn_mfma_f32_16x16x32_f16(a, bf[nf], acc[mf][nf], 0, 0, 0);
        }
    };

    STAGE(0, 0);
    __syncthreads();
    int buf = 0;
#pragma unroll
    for (int t = 0; t < 16; t++) {
        if (t < 15) STAGE(buf ^ 1, (t + 1) * BK);
        COMPUTE(buf);
        __syncthreads();
        buf ^= 1;
    }

    const int ln16 = lane & 15;
    const int lg = lane >> 4;
#pragma unroll
    for (int nf = 0; nf < 4; nf++) {
        int col = n0 + wn * 64 + nf * 16 + ln16;
        float bv = bias[col];
        float s = 0.f, qq = 0.f;
#pragma unroll
        for (int mf = 0; mf < 4; mf++) {
#pragma unroll
            for (int r = 0; r < 4; r++) {
                int row = m0 + wm * 64 + mf * 16 + lg * 4 + r;
                if (row < M) {
                    float v = acc[mf][nf][r] + bv;
                    Yh[(size_t)row * DIM + col] = f32_to_f16u(v);
                    s += v; qq += v * v;
                }
            }
        }
        s += __shfl_xor(s, 16);
        s += __shfl_xor(s, 32);
        qq += __shfl_xor(qq, 16);
        qq += __shfl_xor(qq, 32);
        if (lg == 0) {
            atomicAdd(&ssum[col], s);
            atomicAdd(&ssq[col], qq);
        }
    }
}

// ---------------- GEMM2: A = f16(relu(bn1(y1))) fused in staging; B via gl_lds ----------
__global__ __launch_bounds__(256, 4)
void gemm2_kernel(const unsigned short* __restrict__ Yin,
                  const float* __restrict__ s1sum, const float* __restrict__ s1sq,
                  const float* __restrict__ g1l, const float* __restrict__ be1l,
                  float invN,
                  const unsigned short* __restrict__ B,
                  const float* __restrict__ bias,
                  unsigned short* __restrict__ Yh,
                  float* __restrict__ ssum, float* __restrict__ ssq,
                  int M) {
    __shared__ unsigned short lds[2 * BUF_E];   // 32 KB
    __shared__ float spa[DIM], spc[DIM];        // +4 KB

    const int tid = threadIdx.x;
    const int lane = tid & 63;
    const int wave = tid >> 6;
    const int wm = wave >> 1, wn = wave & 1;

    for (int d = tid; d < DIM; d += 256) {
        float a, c;
        bn_params(s1sum[d], s1sq[d], g1l[d], be1l[d], invN, a, c);
        spa[d] = a; spc[d] = c;
    }
    __syncthreads();

    const int b = blockIdx.x;
    const int xcd = b & 7;
    const int slot_ = b >> 3;
    const int g = (slot_ >> 2) * 8 + xcd;
    const int j = slot_ & 3;
    const int m0 = g * BM;
    const int n0 = j * BN;

    const int r15 = lane & 15;
    const int rslot = ((lane >> 4) ^ ((r15 >> 1) & 3)) * 8;

    f32x4 acc[4][4];
#pragma unroll
    for (int i = 0; i < 4; i++)
#pragma unroll
        for (int jj = 0; jj < 4; jj++) acc[i][jj] = (f32x4){0.f, 0.f, 0.f, 0.f};

    auto STAGE = [&](int bi, int kt) {
        unsigned short* L = lds + bi * BUF_E;
#pragma unroll
        for (int i = 0; i < 2; i++) {
            int slotbase = i * 256 + wave * 64;
            int slot = slotbase + lane;
            int row = slot >> 2;
            int gc = ((slot & 3) ^ ((row >> 1) & 3));
            int colb = kt + gc * 8;
            u16x8 y = *reinterpret_cast<const u16x8*>(Yin + (size_t)(m0 + row) * DIM + colb);
            u16x8 h;
#pragma unroll
            for (int jj = 0; jj < 8; jj++)
                h[jj] = f32_to_f16u(fmaxf(f16u_to_f32(y[jj]) * spa[colb + jj] + spc[colb + jj], 0.f));
            *reinterpret_cast<u16x8*>(&L[slot * 8]) = h;
            gl_lds16(B + (size_t)(n0 + row) * DIM + colb, L + 4096 + slotbase * 8);
        }
    };

    auto COMPUTE = [&](int bi) {
        unsigned short* L = lds + bi * BUF_E;
        f16x8 bf[4];
#pragma unroll
        for (int nf = 0; nf < 4; nf++) {
            int rb = wn * 64 + nf * 16 + r15;
            bf[nf] = *reinterpret_cast<const f16x8*>(&L[4096 + rb * 32 + rslot]);
        }
#pragma unroll
        for (int mf = 0; mf < 4; mf++) {
            int ra = wm * 64 + mf * 16 + r15;
            f16x8 a = *reinterpret_cast<const f16x8*>(&L[ra * 32 + rslot]);
#pragma unroll
            for (int nf = 0; nf < 4; nf++)
                acc[mf][nf] = __builtin_amdgcn_mfma_f32_16x16x32_f16(a, bf[nf], acc[mf][nf], 0, 0, 0);
        }
    };

    STAGE(0, 0);
    __syncthreads();
    int buf = 0;
#pragma unroll
    for (int t = 0; t < 16; t++) {
        if (t < 15) STAGE(buf ^ 1, (t + 1) * BK);
        COMPUTE(buf);
        __syncthreads();
        buf ^= 1;
    }

    const int ln16 = lane & 15;
    const int lg = lane >> 4;
#pragma unroll
    for (int nf = 0; nf < 4; nf++) {
        int col = n0 + wn * 64 + nf * 16 + ln16;
        float bv = bias[col];
        float s = 0.f, qq = 0.f;
#pragma unroll
        for (int mf = 0; mf < 4; mf++) {
#pragma unroll
            for (int r = 0; r < 4; r++) {
                int row = m0 + wm * 64 + mf * 16 + lg * 4 + r;
                if (row < M) {
                    float v = acc[mf][nf][r] + bv;
                    Yh[(size_t)row * DIM + col] = f32_to_f16u(v);
                    s += v; qq += v * v;
                }
            }
        }
        s += __shfl_xor(s, 16);
        s += __shfl_xor(s, 32);
        qq += __shfl_xor(qq, 16);
        qq += __shfl_xor(qq, 32);
        if (lg == 0) {
            atomicAdd(&ssum[col], s);
            atomicAdd(&ssq[col], qq);
        }
    }
}

// ---------------- ustats (l<2): STATS-ONLY pass over u = relu(bn2(y2)) ----------
__global__ void ustats_kernel(const unsigned short* __restrict__ Yh,
                              const float* __restrict__ s2sum, const float* __restrict__ s2sq,
                              const float* __restrict__ g2l, const float* __restrict__ be2l,
                              float invN,
                              float* __restrict__ s3sum, float* __restrict__ s3sq,
                              int M, int chunk) {
    int d = blockIdx.x * blockDim.x + threadIdx.x;
    float a, c;
    bn_params(s2sum[d], s2sq[d], g2l[d], be2l[d], invN, a, c);
    int r0 = blockIdx.y * chunk;
    int r1 = r0 + chunk; if (r1 > M) r1 = M;
    float s = 0.f, q = 0.f;
    for (int r = r0; r < r1; r++) {
        float v = fmaxf(f16u_to_f32(Yh[(size_t)r * DIM + d]) * a + c, 0.f);
        s += v; q += v * v;
    }
    atomicAdd(&s3sum[d], s);
    atomicAdd(&s3sq[d], q);
}

// ---------------- finalize (+ analytic last-layer BN3 params) ----------------
__global__ void finalize_kernel(const unsigned short* __restrict__ Yh,
                                const float* __restrict__ s2sum, const float* __restrict__ s2sq,
                                const float* __restrict__ g2l, const float* __restrict__ be2l,
                                const float* __restrict__ ngl, const float* __restrict__ nbl,
                                float invN,
                                float* __restrict__ out, int total4) {
    __shared__ float sa2[DIM], sc2[DIM], sa3[DIM], sc3[DIM];
    for (int d = threadIdx.x; d < DIM; d += 256) {
        float a2, c2;
        bn_params(s2sum[d], s2sq[d], g2l[d], be2l[d], invN, a2, c2);
        float m_y = s2sum[d] * invN;
        float var_y = fmaxf(s2sq[d] * invN - m_y * m_y, 0.f);
        float m_u = a2 * m_y + c2;
        float var_u = a2 * a2 * var_y;
        float a3 = ngl[d] * rsqrtf(var_u + BN_EPS);
        float c3 = nbl[d] - m_u * a3;
        sa2[d] = a2; sc2[d] = c2; sa3[d] = a3; sc3[d] = c3;
    }
    __syncthreads();
    int i = blockIdx.x * blockDim.x + threadIdx.x;
    int stride = gridDim.x * blockDim.x;
    for (; i < total4; i += stride) {
        int c = (i & 127) * 4;
        u16x4 y = *reinterpret_cast<const u16x4*>(Yh + (size_t)i * 4);
        f32x4 v;
#pragma unroll
        for (int j = 0; j < 4; j++) {
            float f = f16u_to_f32(y[j]) * sa2[c + j] + sc2[c + j];
            v[j] = f * sa3[c + j] + sc3[c + j];
        }
        *reinterpret_cast<f32x4*>(out + (size_t)i * 4) = v;
    }
}

extern "C" void kernel_launch(void* const* d_in, const int* in_sizes, int n_in,
                              void* d_out, int out_size, void* d_ws, size_t ws_size,
                              hipStream_t stream) {
    const float* x   = (const float*)d_in[0];
    const int*   ei  = (const int*)d_in[1];
    const float* W1  = (const float*)d_in[2];
    const float* b1  = (const float*)d_in[3];
    const float* g1  = (const float*)d_in[4];
    const float* be1 = (const float*)d_in[5];
    const float* W2  = (const float*)d_in[6];
    const float* b2  = (const float*)d_in[7];
    const float* g2  = (const float*)d_in[8];
    const float* be2 = (const float*)d_in[9];
    const float* ng  = (const float*)d_in[10];
    const float* nb  = (const float*)d_in[11];

    const int N = in_sizes[0] / DIM;
    const int E = in_sizes[1] / 2;

    char* ws = (char*)d_ws;
    size_t off = 0;
    auto alloc = [&](size_t bytes) -> void* {
        void* p = ws + off;
        off += (bytes + 255) & ~(size_t)255;
        return p;
    };
    // Rotation: P2 = x-fp16 then y2; P0 = agg out (gemm A); P1 = y1.
    unsigned short* P0 = (unsigned short*)alloc((size_t)N * DIM * 2);
    unsigned short* P2 = (unsigned short*)alloc((size_t)N * DIM * 2);
    unsigned short* P1 = (unsigned short*)alloc((size_t)N * DIM * 2);
    unsigned short* Wf = (unsigned short*)alloc(6ull * DIM * DIM * 2);
    int* rowptr = (int*)alloc((size_t)(N + 1) * 4);
    int* counts = (int*)alloc((size_t)N * 4);
    int* cursor = (int*)alloc((size_t)N * 4);
    int* colsrc = (int*)alloc((size_t)E * 4);
    int* bsum   = (int*)alloc(1024 * 4);
    float* stats = (float*)alloc(9ull * 1024 * 4);

    float* Yout = (float*)d_out;

    hipMemsetAsync(counts, 0, (size_t)N * 4, stream);

    const int NBs = (N + 255) / 256;
    const int total8 = N * DIM / 8;

    prep_kernel<<<PREP_W + PREP_X + PREP_C + 1, 256, 0, stream>>>(
        W1, W2, x, ei, Wf, P2, counts, stats, total8, E);
    scan1<<<NBs, 256, 0, stream>>>(counts, rowptr, bsum, N);
    scan3b<<<NBs, 256, 0, stream>>>(bsum, rowptr, cursor, N, E);
    csr_fill<<<(E + 255) / 256, 256, 0, stream>>>(ei, cursor, colsrc, E);

    const float invN = 1.0f / (float)N;
    const int Gm = (((N + BM - 1) / BM) + 7) & ~7;   // 392 m-panels
    const int gemm_blocks = Gm * 4;
    const int uchunk = (N + 199) / 200;

    for (int l = 0; l < NLAYERS; l++) {
        float* st1 = stats + (size_t)l * 3 * 1024;
        float* st2 = st1 + 1024;
        float* st3 = st2 + 1024;
        if (l == 0)
            agg_b<0><<<N, 128, 0, stream>>>(P2, rowptr, colsrc,
                                            nullptr, nullptr, nullptr, nullptr,
                                            nullptr, nullptr, nullptr, nullptr,
                                            invN, P0, N);
        else {
            float* p2s = stats + (size_t)(l - 1) * 3 * 1024 + 1024;   // prev st2
            float* p3s = p2s + 1024;                                   // prev st3
            agg_b<1><<<N, 128, 0, stream>>>(P2, rowptr, colsrc,
                                            p2s, p2s + 512, g2 + (l - 1) * DIM, be2 + (l - 1) * DIM,
                                            p3s, p3s + 512, ng + (l - 1) * DIM, nb + (l - 1) * DIM,
                                            invN, P0, N);
        }
        gemm_kernel<<<gemm_blocks, 256, 0, stream>>>(P0,
            Wf + (size_t)(l * 2) * DIM * DIM, b1 + l * DIM, P1, st1, st1 + 512, N);
        gemm2_kernel<<<gemm_blocks, 256, 0, stream>>>(P1,
            st1, st1 + 512, g1 + l * DIM, be1 + l * DIM, invN,
            Wf + (size_t)(l * 2 + 1) * DIM * DIM, b2 + l * DIM, P2, st2, st2 + 512, N);
        if (l < NLAYERS - 1)
            ustats_kernel<<<dim3(2, 200), 256, 0, stream>>>(P2, st2, st2 + 512,
                                                            g2 + l * DIM, be2 + l * DIM, invN,
                                                            st3, st3 + 512, N, uchunk);
    }
    {
        int l = NLAYERS - 1;
        float* st2 = stats + (size_t)l * 3 * 1024 + 1024;
        finalize_kernel<<<2048, 256, 0, stream>>>(P2, st2, st2 + 512,
                                                  g2 + l * DIM, be2 + l * DIM,
                                                  ng + l * DIM, nb + l * DIM, invN,
                                                  Yout, N * DIM / 4);
    }
}

// Round 22
// 1015.006 us; speedup vs baseline: 1.2699x; 1.0698x over previous
//
#include <hip/hip_runtime.h>
#include <cstdint>
#include <cstddef>

#define DIM 512
#define NLAYERS 3
#define BM 128
#define BN 128
#define BK 32
#define BUF_E 8192    // elems per buffer: A 4096 + B 4096 (16 KB)
#define BN_EPS 1e-5f
#define PREP_W 1536
#define PREP_X 1024
#define PREP_C 784

typedef float f32x4 __attribute__((ext_vector_type(4)));
typedef _Float16 f16x8 __attribute__((ext_vector_type(8)));
typedef unsigned short u16x4 __attribute__((ext_vector_type(4)));
typedef unsigned short u16x8 __attribute__((ext_vector_type(8)));

__device__ __forceinline__ unsigned short f32_to_f16u(float f) {
    _Float16 h = (_Float16)f;
    return __builtin_bit_cast(unsigned short, h);
}
__device__ __forceinline__ float f16u_to_f32(unsigned short u) {
    return (float)__builtin_bit_cast(_Float16, u);
}

__device__ __forceinline__ void gl_lds16(const unsigned short* g, unsigned short* l) {
    __builtin_amdgcn_global_load_lds(
        (const __attribute__((address_space(1))) void*)g,
        (__attribute__((address_space(3))) void*)l,
        16, 0, 0);
}

__device__ __forceinline__ void bn_params(float ssum, float ssq, float g, float b,
                                          float invN, float& a, float& c) {
    float m = ssum * invN;
    float var = fmaxf(ssq * invN - m * m, 0.f);
    a = g * rsqrtf(var + BN_EPS);
    c = b - m * a;
}

// ---------------- fused prep: W->fp16T | x->fp16 | csr_count | stats zero ----------------
__global__ void prep_kernel(const float* __restrict__ W1, const float* __restrict__ W2,
                            const float* __restrict__ X, const int* __restrict__ ei,
                            unsigned short* __restrict__ Wf, unsigned short* __restrict__ Xh,
                            int* __restrict__ counts, float* __restrict__ stats,
                            int total8, int E) {
    int blk = blockIdx.x;
    if (blk < PREP_W) {
        int id = blk * 256 + threadIdx.x;
        int mat = id >> 16;
        int k4 = (id >> 9) & 127;
        int n = id & 511;
        const float* W = (mat & 1) ? W2 : W1;
        const float* base = W + (size_t)(mat >> 1) * DIM * DIM;
        u16x4 h;
#pragma unroll
        for (int j = 0; j < 4; j++)
            h[j] = f32_to_f16u(base[(size_t)(k4 * 4 + j) * DIM + n]);
        size_t o = ((size_t)mat * DIM + n) * DIM + k4 * 4;
        *reinterpret_cast<u16x4*>(Wf + o) = h;
    } else if (blk < PREP_W + PREP_X) {
        int i = (blk - PREP_W) * 256 + threadIdx.x;
        int stride = PREP_X * 256;
        for (; i < total8; i += stride) {
            f32x4 v0 = *reinterpret_cast<const f32x4*>(X + (size_t)i * 8);
            f32x4 v1 = *reinterpret_cast<const f32x4*>(X + (size_t)i * 8 + 4);
            u16x8 h;
#pragma unroll
            for (int j = 0; j < 4; j++) h[j] = f32_to_f16u(v0[j]);
#pragma unroll
            for (int j = 0; j < 4; j++) h[4 + j] = f32_to_f16u(v1[j]);
            __builtin_nontemporal_store(h, reinterpret_cast<u16x8*>(Xh + (size_t)i * 8));
        }
    } else if (blk < PREP_W + PREP_X + PREP_C) {
        int i = (blk - PREP_W - PREP_X) * 256 + threadIdx.x;
        int stride = PREP_C * 256;
        for (; i < E; i += stride) atomicAdd(&counts[ei[E + i]], 1);
    } else {
        for (int i = threadIdx.x; i < 9 * 1024; i += 256) stats[i] = 0.f;
    }
}

// ---------------- CSR scan (2 dispatches) ----------------
__global__ void scan1(const int* __restrict__ counts, int* __restrict__ rowptr,
                      int* __restrict__ bsum, int N) {
    __shared__ int sh[256];
    int t = threadIdx.x;
    int i = blockIdx.x * 256 + t;
    int v = (i < N) ? counts[i] : 0;
    sh[t] = v;
    __syncthreads();
    for (int d = 1; d < 256; d <<= 1) {
        int u = (t >= d) ? sh[t - d] : 0;
        __syncthreads();
        sh[t] += u;
        __syncthreads();
    }
    if (i < N) rowptr[i] = sh[t] - v;
    if (t == 255) bsum[blockIdx.x] = sh[255];
}

__global__ void scan3b(const int* __restrict__ bsum, int* __restrict__ rowptr,
                       int* __restrict__ cursor, int N, int E) {
    __shared__ int sh[256];
    int t = threadIdx.x;
    int bid = blockIdx.x;
    sh[t] = (t < bid) ? bsum[t] : 0;
    __syncthreads();
    for (int d = 128; d > 0; d >>= 1) {
        if (t < d) sh[t] += sh[t + d];
        __syncthreads();
    }
    int off = sh[0];
    int i = bid * 256 + t;
    if (i < N) {
        int r = rowptr[i] + off;
        rowptr[i] = r;
        cursor[i] = r;
    }
    if (bid == 0 && t == 0) rowptr[N] = E;
}

__global__ void csr_fill(const int* __restrict__ ei, int* __restrict__ cursor,
                         int* __restrict__ colsrc, int E) {
    int e = blockIdx.x * 256 + threadIdx.x;
    if (e < E) {
        int s = ei[e], d = ei[E + e];
        int p = atomicAdd(&cursor[d], 1);
        colsrc[p] = s;
    }
}

// ---------------- aggregation over fp16 rows -> fp16 A-plane ----------------
template<int MODE>
__global__ void agg_b(const unsigned short* __restrict__ U,
                      const int* __restrict__ rowptr, const int* __restrict__ colsrc,
                      const float* __restrict__ s2sum, const float* __restrict__ s2sq,
                      const float* __restrict__ g2l, const float* __restrict__ be2l,
                      const float* __restrict__ s3sum, const float* __restrict__ s3sq,
                      const float* __restrict__ ngl, const float* __restrict__ nbl,
                      float invN,
                      unsigned short* __restrict__ Phi, int N) {
    int n = blockIdx.x;
    int c = threadIdx.x * 4;
    f32x4 a2, c2, a3, c3;
    if (MODE) {
#pragma unroll
        for (int j = 0; j < 4; j++) {
            float a, cc;
            bn_params(s2sum[c + j], s2sq[c + j], g2l[c + j], be2l[c + j], invN, a, cc);
            a2[j] = a; c2[j] = cc;
            bn_params(s3sum[c + j], s3sq[c + j], ngl[c + j], nbl[c + j], invN, a, cc);
            a3[j] = a; c3[j] = cc;
        }
    }
    auto ldT = [&](int r) -> f32x4 {
        u16x4 u = *reinterpret_cast<const u16x4*>(U + (size_t)r * DIM + c);
        f32x4 v;
#pragma unroll
        for (int j = 0; j < 4; j++) {
            float f = f16u_to_f32(u[j]);
            if (MODE) {
                f = fmaxf(f * a2[j] + c2[j], 0.f);
                f = fmaxf(f * a3[j] + c3[j], 0.f);
            }
            v[j] = f;
        }
        return v;
    };
    f32x4 acc = ldT(n);
    int e0 = rowptr[n], e1 = rowptr[n + 1];
    int e = e0;
    for (; e + 8 <= e1; e += 8) {
        int s0 = colsrc[e],     s1 = colsrc[e + 1], s2 = colsrc[e + 2], s3 = colsrc[e + 3];
        int s4 = colsrc[e + 4], s5 = colsrc[e + 5], s6 = colsrc[e + 6], s7 = colsrc[e + 7];
        f32x4 v0 = ldT(s0);
        f32x4 v1 = ldT(s1);
        f32x4 v2 = ldT(s2);
        f32x4 v3 = ldT(s3);
        f32x4 v4 = ldT(s4);
        f32x4 v5 = ldT(s5);
        f32x4 v6 = ldT(s6);
        f32x4 v7 = ldT(s7);
        acc += v0; acc += v1; acc += v2; acc += v3;
        acc += v4; acc += v5; acc += v6; acc += v7;
    }
    for (; e < e1; e++) acc += ldT(colsrc[e]);
    u16x4 h;
#pragma unroll
    for (int j = 0; j < 4; j++) h[j] = f32_to_f16u(acc[j]);
    *reinterpret_cast<u16x4*>(Phi + (size_t)n * DIM + c) = h;
}

// ---------------- GEMM1: fp16 single-plane, 128x128, BK=32, dbuf ----------
__global__ __launch_bounds__(256, 4)
void gemm_kernel(const unsigned short* __restrict__ A,
                 const unsigned short* __restrict__ B,
                 const float* __restrict__ bias,
                 unsigned short* __restrict__ Yh,
                 float* __restrict__ ssum, float* __restrict__ ssq,
                 int M) {
    __shared__ unsigned short lds[2 * BUF_E];   // 32 KB

    const int tid = threadIdx.x;
    const int lane = tid & 63;
    const int wave = tid >> 6;
    const int wm = wave >> 1, wn = wave & 1;

    const int b = blockIdx.x;
    const int xcd = b & 7;
    const int slot_ = b >> 3;
    const int g = (slot_ >> 2) * 8 + xcd;
    const int j = slot_ & 3;
    const int m0 = g * BM;
    const int n0 = j * BN;

    const int r15 = lane & 15;
    const int rslot = ((lane >> 4) ^ ((r15 >> 1) & 3)) * 8;

    f32x4 acc[4][4];
#pragma unroll
    for (int i = 0; i < 4; i++)
#pragma unroll
        for (int jj = 0; jj < 4; jj++) acc[i][jj] = (f32x4){0.f, 0.f, 0.f, 0.f};

    auto STAGE = [&](int bi, int kt) {
        unsigned short* L = lds + bi * BUF_E;
#pragma unroll
        for (int i = 0; i < 2; i++) {
            int slotbase = i * 256 + wave * 64;
            int slot = slotbase + lane;
            int row = slot >> 2;
            int gc = ((slot & 3) ^ ((row >> 1) & 3)) * 8;
            gl_lds16(A + (size_t)(m0 + row) * DIM + kt + gc, L + slotbase * 8);
            gl_lds16(B + (size_t)(n0 + row) * DIM + kt + gc, L + 4096 + slotbase * 8);
        }
    };

    auto COMPUTE = [&](int bi) {
        unsigned short* L = lds + bi * BUF_E;
        f16x8 bf[4];
#pragma unroll
        for (int nf = 0; nf < 4; nf++) {
            int rb = wn * 64 + nf * 16 + r15;
            bf[nf] = *reinterpret_cast<const f16x8*>(&L[4096 + rb * 32 + rslot]);
        }
#pragma unroll
        for (int mf = 0; mf < 4; mf++) {
            int ra = wm * 64 + mf * 16 + r15;
            f16x8 a = *reinterpret_cast<const f16x8*>(&L[ra * 32 + rslot]);
#pragma unroll
            for (int nf = 0; nf < 4; nf++)
                acc[mf][nf] = __builtin_amdgcn_mfma_f32_16x16x32_f16(a, bf[nf], acc[mf][nf], 0, 0, 0);
        }
    };

    STAGE(0, 0);
    __syncthreads();
    int buf = 0;
#pragma unroll
    for (int t = 0; t < 16; t++) {
        if (t < 15) STAGE(buf ^ 1, (t + 1) * BK);
        COMPUTE(buf);
        __syncthreads();
        buf ^= 1;
    }

    const int ln16 = lane & 15;
    const int lg = lane >> 4;
#pragma unroll
    for (int nf = 0; nf < 4; nf++) {
        int col = n0 + wn * 64 + nf * 16 + ln16;
        float bv = bias[col];
        float s = 0.f, qq = 0.f;
#pragma unroll
        for (int mf = 0; mf < 4; mf++) {
#pragma unroll
            for (int r = 0; r < 4; r++) {
                int row = m0 + wm * 64 + mf * 16 + lg * 4 + r;
                if (row < M) {
                    float v = acc[mf][nf][r] + bv;
                    Yh[(size_t)row * DIM + col] = f32_to_f16u(v);
                    s += v; qq += v * v;
                }
            }
        }
        s += __shfl_xor(s, 16);
        s += __shfl_xor(s, 32);
        qq += __shfl_xor(qq, 16);
        qq += __shfl_xor(qq, 32);
        if (lg == 0) {
            atomicAdd(&ssum[col], s);
            atomicAdd(&ssq[col], qq);
        }
    }
}

// ---------------- GEMM2: A = f16(relu(bn1(y1))) fused in staging; B via gl_lds ----------
__global__ __launch_bounds__(256, 4)
void gemm2_kernel(const unsigned short* __restrict__ Yin,
                  const float* __restrict__ s1sum, const float* __restrict__ s1sq,
                  const float* __restrict__ g1l, const float* __restrict__ be1l,
                  float invN,
                  const unsigned short* __restrict__ B,
                  const float* __restrict__ bias,
                  unsigned short* __restrict__ Yh,
                  float* __restrict__ ssum, float* __restrict__ ssq,
                  int M) {
    __shared__ unsigned short lds[2 * BUF_E];   // 32 KB
    __shared__ float spa[DIM], spc[DIM];        // +4 KB

    const int tid = threadIdx.x;
    const int lane = tid & 63;
    const int wave = tid >> 6;
    const int wm = wave >> 1, wn = wave & 1;

    for (int d = tid; d < DIM; d += 256) {
        float a, c;
        bn_params(s1sum[d], s1sq[d], g1l[d], be1l[d], invN, a, c);
        spa[d] = a; spc[d] = c;
    }
    __syncthreads();

    const int b = blockIdx.x;
    const int xcd = b & 7;
    const int slot_ = b >> 3;
    const int g = (slot_ >> 2) * 8 + xcd;
    const int j = slot_ & 3;
    const int m0 = g * BM;
    const int n0 = j * BN;

    const int r15 = lane & 15;
    const int rslot = ((lane >> 4) ^ ((r15 >> 1) & 3)) * 8;

    f32x4 acc[4][4];
#pragma unroll
    for (int i = 0; i < 4; i++)
#pragma unroll
        for (int jj = 0; jj < 4; jj++) acc[i][jj] = (f32x4){0.f, 0.f, 0.f, 0.f};

    auto STAGE = [&](int bi, int kt) {
        unsigned short* L = lds + bi * BUF_E;
#pragma unroll
        for (int i = 0; i < 2; i++) {
            int slotbase = i * 256 + wave * 64;
            int slot = slotbase + lane;
            int row = slot >> 2;
            int gc = ((slot & 3) ^ ((row >> 1) & 3));
            int colb = kt + gc * 8;
            u16x8 y = *reinterpret_cast<const u16x8*>(Yin + (size_t)(m0 + row) * DIM + colb);
            u16x8 h;
#pragma unroll
            for (int jj = 0; jj < 8; jj++)
                h[jj] = f32_to_f16u(fmaxf(f16u_to_f32(y[jj]) * spa[colb + jj] + spc[colb + jj], 0.f));
            *reinterpret_cast<u16x8*>(&L[slot * 8]) = h;
            gl_lds16(B + (size_t)(n0 + row) * DIM + colb, L + 4096 + slotbase * 8);
        }
    };

    auto COMPUTE = [&](int bi) {
        unsigned short* L = lds + bi * BUF_E;
        f16x8 bf[4];
#pragma unroll
        for (int nf = 0; nf < 4; nf++) {
            int rb = wn * 64 + nf * 16 + r15;
            bf[nf] = *reinterpret_cast<const f16x8*>(&L[4096 + rb * 32 + rslot]);
        }
#pragma unroll
        for (int mf = 0; mf < 4; mf++) {
            int ra = wm * 64 + mf * 16 + r15;
            f16x8 a = *reinterpret_cast<const f16x8*>(&L[ra * 32 + rslot]);
#pragma unroll
            for (int nf = 0; nf < 4; nf++)
                acc[mf][nf] = __builtin_amdgcn_mfma_f32_16x16x32_f16(a, bf[nf], acc[mf][nf], 0, 0, 0);
        }
    };

    STAGE(0, 0);
    __syncthreads();
    int buf = 0;
#pragma unroll
    for (int t = 0; t < 16; t++) {
        if (t < 15) STAGE(buf ^ 1, (t + 1) * BK);
        COMPUTE(buf);
        __syncthreads();
        buf ^= 1;
    }

    const int ln16 = lane & 15;
    const int lg = lane >> 4;
#pragma unroll
    for (int nf = 0; nf < 4; nf++) {
        int col = n0 + wn * 64 + nf * 16 + ln16;
        float bv = bias[col];
        float s = 0.f, qq = 0.f;
#pragma unroll
        for (int mf = 0; mf < 4; mf++) {
#pragma unroll
            for (int r = 0; r < 4; r++) {
                int row = m0 + wm * 64 + mf * 16 + lg * 4 + r;
                if (row < M) {
                    float v = acc[mf][nf][r] + bv;
                    Yh[(size_t)row * DIM + col] = f32_to_f16u(v);
                    s += v; qq += v * v;
                }
            }
        }
        s += __shfl_xor(s, 16);
        s += __shfl_xor(s, 32);
        qq += __shfl_xor(qq, 16);
        qq += __shfl_xor(qq, 32);
        if (lg == 0) {
            atomicAdd(&ssum[col], s);
            atomicAdd(&ssq[col], qq);
        }
    }
}

// ---------------- ustats (l<2): STATS-ONLY pass over u = relu(bn2(y2)) ----------
__global__ void ustats_kernel(const unsigned short* __restrict__ Yh,
                              const float* __restrict__ s2sum, const float* __restrict__ s2sq,
                              const float* __restrict__ g2l, const float* __restrict__ be2l,
                              float invN,
                              float* __restrict__ s3sum, float* __restrict__ s3sq,
                              int M, int chunk) {
    int d = blockIdx.x * blockDim.x + threadIdx.x;
    float a, c;
    bn_params(s2sum[d], s2sq[d], g2l[d], be2l[d], invN, a, c);
    int r0 = blockIdx.y * chunk;
    int r1 = r0 + chunk; if (r1 > M) r1 = M;
    float s = 0.f, q = 0.f;
    for (int r = r0; r < r1; r++) {
        float v = fmaxf(f16u_to_f32(Yh[(size_t)r * DIM + d]) * a + c, 0.f);
        s += v; q += v * v;
    }
    atomicAdd(&s3sum[d], s);
    atomicAdd(&s3sq[d], q);
}

// ---------------- finalize (+ analytic last-layer BN3 params) ----------------
__global__ void finalize_kernel(const unsigned short* __restrict__ Yh,
                                const float* __restrict__ s2sum, const float* __restrict__ s2sq,
                                const float* __restrict__ g2l, const float* __restrict__ be2l,
                                const float* __restrict__ ngl, const float* __restrict__ nbl,
                                float invN,
                                float* __restrict__ out, int total4) {
    __shared__ float sa2[DIM], sc2[DIM], sa3[DIM], sc3[DIM];
    for (int d = threadIdx.x; d < DIM; d += 256) {
        float a2, c2;
        bn_params(s2sum[d], s2sq[d], g2l[d], be2l[d], invN, a2, c2);
        float m_y = s2sum[d] * invN;
        float var_y = fmaxf(s2sq[d] * invN - m_y * m_y, 0.f);
        float m_u = a2 * m_y + c2;
        float var_u = a2 * a2 * var_y;
        float a3 = ngl[d] * rsqrtf(var_u + BN_EPS);
        float c3 = nbl[d] - m_u * a3;
        sa2[d] = a2; sc2[d] = c2; sa3[d] = a3; sc3[d] = c3;
    }
    __syncthreads();
    int i = blockIdx.x * blockDim.x + threadIdx.x;
    int stride = gridDim.x * blockDim.x;
    for (; i < total4; i += stride) {
        int c = (i & 127) * 4;
        u16x4 y = *reinterpret_cast<const u16x4*>(Yh + (size_t)i * 4);
        f32x4 v;
#pragma unroll
        for (int j = 0; j < 4; j++) {
            float f = f16u_to_f32(y[j]) * sa2[c + j] + sc2[c + j];
            v[j] = f * sa3[c + j] + sc3[c + j];
        }
        *reinterpret_cast<f32x4*>(out + (size_t)i * 4) = v;
    }
}

extern "C" void kernel_launch(void* const* d_in, const int* in_sizes, int n_in,
                              void* d_out, int out_size, void* d_ws, size_t ws_size,
                              hipStream_t stream) {
    const float* x   = (const float*)d_in[0];
    const int*   ei  = (const int*)d_in[1];
    const float* W1  = (const float*)d_in[2];
    const float* b1  = (const float*)d_in[3];
    const float* g1  = (const float*)d_in[4];
    const float* be1 = (const float*)d_in[5];
    const float* W2  = (const float*)d_in[6];
    const float* b2  = (const float*)d_in[7];
    const float* g2  = (const float*)d_in[8];
    const float* be2 = (const float*)d_in[9];
    const float* ng  = (const float*)d_in[10];
    const float* nb  = (const float*)d_in[11];

    const int N = in_sizes[0] / DIM;
    const int E = in_sizes[1] / 2;

    char* ws = (char*)d_ws;
    size_t off = 0;
    auto alloc = [&](size_t bytes) -> void* {
        void* p = ws + off;
        off += (bytes + 255) & ~(size_t)255;
        return p;
    };
    unsigned short* P0 = (unsigned short*)alloc((size_t)N * DIM * 2);
    unsigned short* P2 = (unsigned short*)alloc((size_t)N * DIM * 2);
    unsigned short* P1 = (unsigned short*)alloc((size_t)N * DIM * 2);
    unsigned short* Wf = (unsigned short*)alloc(6ull * DIM * DIM * 2);
    int* rowptr = (int*)alloc((size_t)(N + 1) * 4);
    int* counts = (int*)alloc((size_t)N * 4);
    int* cursor = (int*)alloc((size_t)N * 4);
    int* colsrc = (int*)alloc((size_t)E * 4);
    int* bsum   = (int*)alloc(1024 * 4);
    float* stats = (float*)alloc(9ull * 1024 * 4);

    float* Yout = (float*)d_out;

    hipMemsetAsync(counts, 0, (size_t)N * 4, stream);

    const int NBs = (N + 255) / 256;
    const int total8 = N * DIM / 8;

    prep_kernel<<<PREP_W + PREP_X + PREP_C + 1, 256, 0, stream>>>(
        W1, W2, x, ei, Wf, P2, counts, stats, total8, E);
    scan1<<<NBs, 256, 0, stream>>>(counts, rowptr, bsum, N);
    scan3b<<<NBs, 256, 0, stream>>>(bsum, rowptr, cursor, N, E);
    csr_fill<<<(E + 255) / 256, 256, 0, stream>>>(ei, cursor, colsrc, E);

    const float invN = 1.0f / (float)N;
    const int Gm = (((N + BM - 1) / BM) + 7) & ~7;   // 392 m-panels
    const int gemm_blocks = Gm * 4;
    const int uy = 800;
    const int uchunk = (N + uy - 1) / uy;

    for (int l = 0; l < NLAYERS; l++) {
        float* st1 = stats + (size_t)l * 3 * 1024;
        float* st2 = st1 + 1024;
        float* st3 = st2 + 1024;
        if (l == 0)
            agg_b<0><<<N, 128, 0, stream>>>(P2, rowptr, colsrc,
                                            nullptr, nullptr, nullptr, nullptr,
                                            nullptr, nullptr, nullptr, nullptr,
                                            invN, P0, N);
        else {
            float* p2s = stats + (size_t)(l - 1) * 3 * 1024 + 1024;   // prev st2
            float* p3s = p2s + 1024;                                   // prev st3
            agg_b<1><<<N, 128, 0, stream>>>(P2, rowptr, colsrc,
                                            p2s, p2s + 512, g2 + (l - 1) * DIM, be2 + (l - 1) * DIM,
                                            p3s, p3s + 512, ng + (l - 1) * DIM, nb + (l - 1) * DIM,
                                            invN, P0, N);
        }
        gemm_kernel<<<gemm_blocks, 256, 0, stream>>>(P0,
            Wf + (size_t)(l * 2) * DIM * DIM, b1 + l * DIM, P1, st1, st1 + 512, N);
        gemm2_kernel<<<gemm_blocks, 256, 0, stream>>>(P1,
            st1, st1 + 512, g1 + l * DIM, be1 + l * DIM, invN,
            Wf + (size_t)(l * 2 + 1) * DIM * DIM, b2 + l * DIM, P2, st2, st2 + 512, N);
        if (l < NLAYERS - 1)
            ustats_kernel<<<dim3(2, uy), 256, 0, stream>>>(P2, st2, st2 + 512,
                                                           g2 + l * DIM, be2 + l * DIM, invN,
                                                           st3, st3 + 512, N, uchunk);
    }
    {
        int l = NLAYERS - 1;
        float* st2 = stats + (size_t)l * 3 * 1024 + 1024;
        finalize_kernel<<<2048, 256, 0, stream>>>(P2, st2, st2 + 512,
                                                  g2 + l * DIM, be2 + l * DIM,
                                                  ng + l * DIM, nb + l * DIM, invN,
                                                  Yout, N * DIM / 4);
    }
}